// Round 5
// baseline (840.218 us; speedup 1.0000x reference)
//
#include <hip/hip_runtime.h>

typedef unsigned short u16;
typedef short bf16x8 __attribute__((ext_vector_type(8)));
typedef float f32x4 __attribute__((ext_vector_type(4)));

#define B_ 2
#define S_ 2048
#define D_ 2048
#define HD_ 128
#define GW 512  // head-group width: 4 heads x 128
#define KB 32
#define VSTRIDE 40

__device__ __forceinline__ float bf2f(u16 h) {
  unsigned u = ((unsigned)h) << 16;
  return __builtin_bit_cast(float, u);
}
__device__ __forceinline__ u16 f2bf(float f) {
  unsigned u = __builtin_bit_cast(unsigned, f);
  u += 0x7FFF + ((u >> 16) & 1);
  return (u16)(u >> 16);
}
__device__ __forceinline__ bf16x8 cvt8(const float* p) {
  float4 a = *(const float4*)p;
  float4 b = *(const float4*)(p + 4);
  bf16x8 r;
  r[0] = (short)f2bf(a.x); r[1] = (short)f2bf(a.y);
  r[2] = (short)f2bf(a.z); r[3] = (short)f2bf(a.w);
  r[4] = (short)f2bf(b.x); r[5] = (short)f2bf(b.y);
  r[6] = (short)f2bf(b.z); r[7] = (short)f2bf(b.w);
  return r;
}

__device__ __forceinline__ void gload16(const void* g, void* lds) {
  __builtin_amdgcn_global_load_lds(
      (const __attribute__((address_space(1))) unsigned*)g,
      (__attribute__((address_space(3))) unsigned*)lds, 16, 0, 0);
}

__device__ __forceinline__ f32x4 mfma16(bf16x8 a, bf16x8 b, f32x4 c) {
  return __builtin_amdgcn_mfma_f32_16x16x32_bf16(a, b, c, 0, 0, 0);
}

// ---------------- GEMM: C = A(M,2048) @ W(N,2048)^T + bias
// A: f32 (AM=0, reg-stage+cvt) or bf16 (AM=1, global_load_lds).
// W: f32 always (reg-stage+cvt). C: bf16 (CM=0) or f32 (CM=1), row stride ldc.
// 128x128 tile, BK=32, 4 waves (2x2), 16x16x32 MFMA (m97 structure).
template <int AM, int CM>
__device__ __forceinline__ void gemm_body(const void* Ap, const float* __restrict__ W,
                                          const float* __restrict__ bias,
                                          void* Cp, int ldc) {
  constexpr int K = 2048;
  __shared__ u16 As[128 * 32];
  __shared__ u16 Bs[128 * 32];
  const int t = threadIdx.x;
  const int w = t >> 6, l = t & 63, lr = l & 15, lg = l >> 4;
  const int m0 = blockIdx.y * 128, n0 = blockIdx.x * 128;
  const int wr = w >> 1, wc = w & 1;

  f32x4 acc[4][4];
#pragma unroll
  for (int i = 0; i < 4; ++i)
#pragma unroll
    for (int j = 0; j < 4; ++j) acc[i][j] = f32x4{0.f, 0.f, 0.f, 0.f};

  const int rowA0 = t >> 2, ko0 = (t & 3) * 8;
  const int rowA1 = (t + 256) >> 2, ko1 = ((t + 256) & 3) * 8;

  for (int kt = 0; kt < K; kt += 32) {
    if constexpr (AM == 1) {
      const u16* A = (const u16*)Ap;
      gload16(A + (size_t)(m0 + rowA0) * K + kt + ko0, (char*)As + (size_t)w * 1024);
      gload16(A + (size_t)(m0 + rowA1) * K + kt + ko1, (char*)As + (size_t)(w + 4) * 1024);
    } else {
      const float* A = (const float*)Ap;
      *(bf16x8*)((char*)As + (size_t)t * 16) = cvt8(A + (size_t)(m0 + rowA0) * K + kt + ko0);
      *(bf16x8*)((char*)As + (size_t)(t + 256) * 16) = cvt8(A + (size_t)(m0 + rowA1) * K + kt + ko1);
    }
    *(bf16x8*)((char*)Bs + (size_t)t * 16) = cvt8(W + (size_t)(n0 + rowA0) * K + kt + ko0);
    *(bf16x8*)((char*)Bs + (size_t)(t + 256) * 16) = cvt8(W + (size_t)(n0 + rowA1) * K + kt + ko1);
    __syncthreads();

    bf16x8 af[4], bw[4];
#pragma unroll
    for (int i = 0; i < 4; ++i) {
      af[i] = *(const bf16x8*)(As + (size_t)(wr * 64 + i * 16 + lr) * 32 + lg * 8);
      bw[i] = *(const bf16x8*)(Bs + (size_t)(wc * 64 + i * 16 + lr) * 32 + lg * 8);
    }
#pragma unroll
    for (int i = 0; i < 4; ++i)
#pragma unroll
      for (int j = 0; j < 4; ++j)
        acc[i][j] = mfma16(af[i], bw[j], acc[i][j]);
    __syncthreads();
  }

#pragma unroll
  for (int i = 0; i < 4; ++i) {
#pragma unroll
    for (int j = 0; j < 4; ++j) {
      const int col = n0 + wc * 64 + j * 16 + lr;
      const float bv = bias[col];
      const int row = m0 + wr * 64 + i * 16 + lg * 4;
#pragma unroll
      for (int r = 0; r < 4; ++r) {
        if constexpr (CM == 1)
          ((float*)Cp)[(size_t)(row + r) * ldc + col] = acc[i][j][r] + bv;
        else
          ((u16*)Cp)[(size_t)(row + r) * ldc + col] = f2bf(acc[i][j][r] + bv);
      }
    }
  }
}

// QKV for one head group g: weight rows [g*512, g*512+512), compact bf16 outputs [4096,512]
__global__ __launch_bounds__(256) void k_gemm_qkv_g(
    const float* __restrict__ x, const float* __restrict__ wq,
    const float* __restrict__ bq, const float* __restrict__ wk,
    const float* __restrict__ bk, const float* __restrict__ wv,
    const float* __restrict__ bv, u16* __restrict__ qg, u16* __restrict__ kg,
    u16* __restrict__ vg, int g) {
  const int z = blockIdx.z;
  const float* W = (z == 0 ? wq : (z == 1 ? wk : wv)) + (size_t)g * GW * D_;
  const float* bias = (z == 0 ? bq : (z == 1 ? bk : bv)) + g * GW;
  u16* C = z == 0 ? qg : (z == 1 ? kg : vg);
  gemm_body<0, 0>(x, W, bias, C, GW);
}

// Final: out(f32) = ao(bf16) @ wo^T + bo
__global__ __launch_bounds__(256) void k_gemm_out(const u16* __restrict__ ao,
                                                  const float* __restrict__ wo,
                                                  const float* __restrict__ bo,
                                                  float* __restrict__ out) {
  gemm_body<1, 1>(ao, wo, bo, out, D_);
}

// ---------------- RoPE (interleaved pairs) in place on compact bf16 [B*S, 512] q,k
__global__ void k_rope_g(u16* q, u16* kk) {
  const int idx = blockIdx.x * 256 + threadIdx.x;  // B*S*4*64 = 1,048,576
  const int i = idx & 63;
  const int hh = (idx >> 6) & 3;
  const int bs = idx >> 8;
  const int s = bs & (S_ - 1);
  const float freq = expf(-(float)i * 0.14391157f);  // ln(10000)/64
  const float ang = (float)s * freq;
  float sv, cv;
  sincosf(ang, &sv, &cv);
  const size_t off = (size_t)bs * GW + (size_t)hh * HD_ + 2 * i;

  unsigned uq = *(const unsigned*)(q + off);
  float x1 = bf2f((u16)(uq & 0xffff)), x2 = bf2f((u16)(uq >> 16));
  unsigned rq = (unsigned)f2bf(x1 * cv - x2 * sv) |
                ((unsigned)f2bf(x1 * sv + x2 * cv) << 16);
  *(unsigned*)(q + off) = rq;

  unsigned uk = *(const unsigned*)(kk + off);
  x1 = bf2f((u16)(uk & 0xffff));
  x2 = bf2f((u16)(uk >> 16));
  unsigned rk = (unsigned)f2bf(x1 * cv - x2 * sv) |
                ((unsigned)f2bf(x1 * sv + x2 * cv) << 16);
  *(unsigned*)(kk + off) = rk;
}

// ---------------- Flash attention (causal) for one head group, all bf16.
// Q/K/V: compact [B*S, 512] (stride GW); O: full [B*S, 2048] (stride D_).
// 64 Q rows/block, 4 waves x 16 rows, KV tiles of 32. K staged swizzled via
// global_load_lds; V reg-staged transposed into padded LDS.
__global__ __launch_bounds__(256) void k_attn_g(const u16* __restrict__ Q,
                                                const u16* __restrict__ Kd,
                                                const u16* __restrict__ V,
                                                u16* __restrict__ O, int g) {
  const int by = blockIdx.y;
  const int b = by >> 2, hh = by & 3;
  const int q0 = blockIdx.x * 64;
  const int t = threadIdx.x, w = t >> 6, l = t & 63, lr = l & 15, lg = l >> 4;

  __shared__ u16 Ks[KB * HD_];       // [32][128], chunk-XOR swizzled
  __shared__ u16 Vt[HD_ * VSTRIDE];  // transposed [128][40-padded]
  __shared__ u16 Ps[4][16 * KB];     // per-wave P tile

  const size_t base_in = ((size_t)b * S_) * GW + (size_t)hh * HD_;
  const size_t base_out = ((size_t)b * S_) * D_ + (size_t)(g * 4 + hh) * HD_;

  bf16x8 qf[4];
  {
    const u16* qp = Q + base_in + (size_t)(q0 + w * 16 + lr) * GW;
#pragma unroll
    for (int ds = 0; ds < 4; ++ds)
      qf[ds] = *(const bf16x8*)(qp + ds * 32 + lg * 8);
  }

  f32x4 oacc[8];
#pragma unroll
  for (int f = 0; f < 8; ++f) oacc[f] = f32x4{0.f, 0.f, 0.f, 0.f};
  float mrow[4] = {-1e30f, -1e30f, -1e30f, -1e30f};
  float lrow[4] = {0.f, 0.f, 0.f, 0.f};

  const int q_hi = q0 + w * 16 + 15;
  const int ntiles = (q0 + 64) / KB;
  const float sc = 0.08838834764831845f;  // 1/sqrt(128)

  for (int tkv = 0; tkv < ntiles; ++tkv) {
    const int kv0 = tkv * KB;
    // stage K (8KB) with XOR-swizzled global source
#pragma unroll
    for (int r = 0; r < 2; ++r) {
      const int c = t + 256 * r;
      const int row = c >> 4, c16 = c & 15;
      const int gc = c16 ^ (row & 7);
      gload16(Kd + base_in + (size_t)(kv0 + row) * GW + gc * 8,
              (char*)Ks + (size_t)(w + 4 * r) * 1024);
    }
    // stage V transposed via regs (k-contiguous LDS rows, 80B stride)
#pragma unroll
    for (int r = 0; r < 2; ++r) {
      const int c = t + 256 * r;
      const int kk = c & 31, d0 = (c >> 5) * 8;
      bf16x8 vv = *(const bf16x8*)(V + base_in + (size_t)(kv0 + kk) * GW + d0);
#pragma unroll
      for (int j = 0; j < 8; ++j) Vt[(size_t)(d0 + j) * VSTRIDE + kk] = (u16)vv[j];
    }
    __syncthreads();

    if (kv0 <= q_hi) {
      // QK^T for two 16-col halves
      f32x4 s0 = {0.f, 0.f, 0.f, 0.f}, s1 = {0.f, 0.f, 0.f, 0.f};
#pragma unroll
      for (int ds = 0; ds < 4; ++ds) {
        const int ch = (ds * 4 + lg) ^ (lr & 7);
        bf16x8 k0 = *(const bf16x8*)(Ks + (size_t)lr * HD_ + ch * 8);
        bf16x8 k1 = *(const bf16x8*)(Ks + (size_t)(16 + lr) * HD_ + ch * 8);
        s0 = mfma16(qf[ds], k0, s0);
        s1 = mfma16(qf[ds], k1, s1);
      }
      float p0[4], p1[4], pmax[4];
#pragma unroll
      for (int j = 0; j < 4; ++j) {
        const int qrow = q0 + w * 16 + lg * 4 + j;
        float a0 = s0[j] * sc;
        if (kv0 + lr > qrow) a0 = -1e30f;
        float a1 = s1[j] * sc;
        if (kv0 + 16 + lr > qrow) a1 = -1e30f;
        p0[j] = a0;
        p1[j] = a1;
        pmax[j] = fmaxf(a0, a1);
      }
#pragma unroll
      for (int mk = 1; mk <= 8; mk <<= 1)
#pragma unroll
        for (int j = 0; j < 4; ++j)
          pmax[j] = fmaxf(pmax[j], __shfl_xor(pmax[j], mk, 64));
      float scl[4], rsum[4];
#pragma unroll
      for (int j = 0; j < 4; ++j) {
        const float mn = fmaxf(mrow[j], pmax[j]);
        scl[j] = __expf(mrow[j] - mn);
        mrow[j] = mn;
        const float e0 = __expf(p0[j] - mn);
        const float e1 = __expf(p1[j] - mn);
        p0[j] = e0;
        p1[j] = e1;
        rsum[j] = e0 + e1;
      }
#pragma unroll
      for (int mk = 1; mk <= 8; mk <<= 1)
#pragma unroll
        for (int j = 0; j < 4; ++j) rsum[j] += __shfl_xor(rsum[j], mk, 64);
#pragma unroll
      for (int j = 0; j < 4; ++j) lrow[j] = lrow[j] * scl[j] + rsum[j];
#pragma unroll
      for (int f = 0; f < 8; ++f)
#pragma unroll
        for (int j = 0; j < 4; ++j) oacc[f][j] *= scl[j];
      // P -> LDS (A-fragment layout), then PV
#pragma unroll
      for (int j = 0; j < 4; ++j) {
        const int prow = lg * 4 + j;
        Ps[w][prow * KB + lr] = f2bf(p0[j]);
        Ps[w][prow * KB + 16 + lr] = f2bf(p1[j]);
      }
      bf16x8 pf = *(const bf16x8*)(&Ps[w][lr * KB + lg * 8]);
#pragma unroll
      for (int f = 0; f < 8; ++f) {
        bf16x8 vf = *(const bf16x8*)(Vt + (size_t)(f * 16 + lr) * VSTRIDE + lg * 8);
        oacc[f] = mfma16(pf, vf, oacc[f]);
      }
    }
    __syncthreads();
  }

  float inv[4];
#pragma unroll
  for (int j = 0; j < 4; ++j) inv[j] = 1.0f / lrow[j];
  u16* Op = O + base_out;
#pragma unroll
  for (int f = 0; f < 8; ++f)
#pragma unroll
    for (int j = 0; j < 4; ++j)
      Op[(size_t)(q0 + w * 16 + lg * 4 + j) * D_ + f * 16 + lr] =
          f2bf(oacc[f][j] * inv[j]);
}

extern "C" void kernel_launch(void* const* d_in, const int* in_sizes, int n_in,
                              void* d_out, int out_size, void* d_ws,
                              size_t ws_size, hipStream_t stream) {
  (void)in_sizes; (void)n_in; (void)out_size; (void)ws_size;
  const float* x = (const float*)d_in[0];
  const float* wq = (const float*)d_in[1];
  const float* bq = (const float*)d_in[2];
  const float* wk = (const float*)d_in[3];
  const float* bk = (const float*)d_in[4];
  const float* wv = (const float*)d_in[5];
  const float* bv = (const float*)d_in[6];
  const float* wo = (const float*)d_in[7];
  const float* bo = (const float*)d_in[8];
  float* out = (float*)d_out;

  // Scratch plan: d_out is 33.5 MB (f32 output) -> per-group compact bf16
  // q/k/v ([4096,512] x3 = 12.6 MB) live at the front of d_out; they are dead
  // before the final GEMM overwrites d_out (final GEMM reads only ao/wo/bo).
  // ao (full bf16 [4096,2048] = 16.77 MB) lives in ws.
  u16* qg = (u16*)d_out;
  u16* kg = qg + (size_t)(B_ * S_) * GW;
  u16* vg = kg + (size_t)(B_ * S_) * GW;
  u16* ao = (u16*)d_ws;

  for (int g = 0; g < 4; ++g) {
    dim3 g1(4, 32, 3);
    k_gemm_qkv_g<<<g1, 256, 0, stream>>>(x, wq, bq, wk, bk, wv, bv, qg, kg, vg, g);
    k_rope_g<<<4096, 256, 0, stream>>>(qg, kg);
    dim3 g2(32, 8);
    k_attn_g<<<g2, 256, 0, stream>>>(qg, kg, vg, ao, g);
  }
  dim3 g3(16, 32);
  k_gemm_out<<<g3, 256, 0, stream>>>(ao, wo, bo, out);
}

// Round 6
// 518.857 us; speedup vs baseline: 1.6194x; 1.6194x over previous
//
#include <hip/hip_runtime.h>

typedef unsigned short u16;
typedef short bf16x8 __attribute__((ext_vector_type(8)));
typedef float f32x4 __attribute__((ext_vector_type(4)));

#define B_ 2
#define S_ 2048
#define D_ 2048
#define HD_ 128
#define GW 512  // head-group width for fallback path
#define KB 32
#define VSTRIDE 40

__device__ __forceinline__ float bf2f(u16 h) {
  unsigned u = ((unsigned)h) << 16;
  return __builtin_bit_cast(float, u);
}
__device__ __forceinline__ u16 f2bf(float f) {
  unsigned u = __builtin_bit_cast(unsigned, f);
  u += 0x7FFF + ((u >> 16) & 1);
  return (u16)(u >> 16);
}
__device__ __forceinline__ bf16x8 cvt8(const float* p) {
  float4 a = *(const float4*)p;
  float4 b = *(const float4*)(p + 4);
  bf16x8 r;
  r[0] = (short)f2bf(a.x); r[1] = (short)f2bf(a.y);
  r[2] = (short)f2bf(a.z); r[3] = (short)f2bf(a.w);
  r[4] = (short)f2bf(b.x); r[5] = (short)f2bf(b.y);
  r[6] = (short)f2bf(b.z); r[7] = (short)f2bf(b.w);
  return r;
}

__device__ __forceinline__ void gload16(const void* g, void* lds) {
  __builtin_amdgcn_global_load_lds(
      (const __attribute__((address_space(1))) unsigned*)g,
      (__attribute__((address_space(3))) unsigned*)lds, 16, 0, 0);
}

__device__ __forceinline__ f32x4 mfma16(bf16x8 a, bf16x8 b, f32x4 c) {
  return __builtin_amdgcn_mfma_f32_16x16x32_bf16(a, b, c, 0, 0, 0);
}

// ---------------- GEMM: C = A(M,2048) @ W(N,2048)^T + bias
// A: f32 (AM=0, reg-stage+cvt) or bf16 (AM=1, global_load_lds).
// W: f32 always (reg-stage+cvt). C: bf16 (CM=0) or f32 (CM=1), row stride ldc.
// 128x128 tile, BK=32, 4 waves (2x2), 16x16x32 MFMA (m97 structure).
template <int AM, int CM>
__device__ __forceinline__ void gemm_body(const void* Ap, const float* __restrict__ W,
                                          const float* __restrict__ bias,
                                          void* Cp, int ldc) {
  constexpr int K = 2048;
  __shared__ u16 As[128 * 32];
  __shared__ u16 Bs[128 * 32];
  const int t = threadIdx.x;
  const int w = t >> 6, l = t & 63, lr = l & 15, lg = l >> 4;
  const int m0 = blockIdx.y * 128, n0 = blockIdx.x * 128;
  const int wr = w >> 1, wc = w & 1;

  f32x4 acc[4][4];
#pragma unroll
  for (int i = 0; i < 4; ++i)
#pragma unroll
    for (int j = 0; j < 4; ++j) acc[i][j] = f32x4{0.f, 0.f, 0.f, 0.f};

  const int rowA0 = t >> 2, ko0 = (t & 3) * 8;
  const int rowA1 = (t + 256) >> 2, ko1 = ((t + 256) & 3) * 8;

  for (int kt = 0; kt < K; kt += 32) {
    if constexpr (AM == 1) {
      const u16* A = (const u16*)Ap;
      gload16(A + (size_t)(m0 + rowA0) * K + kt + ko0, (char*)As + (size_t)w * 1024);
      gload16(A + (size_t)(m0 + rowA1) * K + kt + ko1, (char*)As + (size_t)(w + 4) * 1024);
    } else {
      const float* A = (const float*)Ap;
      *(bf16x8*)((char*)As + (size_t)t * 16) = cvt8(A + (size_t)(m0 + rowA0) * K + kt + ko0);
      *(bf16x8*)((char*)As + (size_t)(t + 256) * 16) = cvt8(A + (size_t)(m0 + rowA1) * K + kt + ko1);
    }
    *(bf16x8*)((char*)Bs + (size_t)t * 16) = cvt8(W + (size_t)(n0 + rowA0) * K + kt + ko0);
    *(bf16x8*)((char*)Bs + (size_t)(t + 256) * 16) = cvt8(W + (size_t)(n0 + rowA1) * K + kt + ko1);
    __syncthreads();

    bf16x8 af[4], bw[4];
#pragma unroll
    for (int i = 0; i < 4; ++i) {
      af[i] = *(const bf16x8*)(As + (size_t)(wr * 64 + i * 16 + lr) * 32 + lg * 8);
      bw[i] = *(const bf16x8*)(Bs + (size_t)(wc * 64 + i * 16 + lr) * 32 + lg * 8);
    }
#pragma unroll
    for (int i = 0; i < 4; ++i)
#pragma unroll
      for (int j = 0; j < 4; ++j)
        acc[i][j] = mfma16(af[i], bw[j], acc[i][j]);
    __syncthreads();
  }

#pragma unroll
  for (int i = 0; i < 4; ++i) {
#pragma unroll
    for (int j = 0; j < 4; ++j) {
      const int col = n0 + wc * 64 + j * 16 + lr;
      const float bv = bias[col];
      const int row = m0 + wr * 64 + i * 16 + lg * 4;
#pragma unroll
      for (int r = 0; r < 4; ++r) {
        if constexpr (CM == 1)
          ((float*)Cp)[(size_t)(row + r) * ldc + col] = acc[i][j][r] + bv;
        else
          ((u16*)Cp)[(size_t)(row + r) * ldc + col] = f2bf(acc[i][j][r] + bv);
      }
    }
  }
}

// ---- merged QKV GEMM: full [4096,2048] bf16 outputs, grid (16,32,3)
__global__ __launch_bounds__(256) void k_gemm_qkv_full(
    const float* __restrict__ x, const float* __restrict__ wq,
    const float* __restrict__ bq, const float* __restrict__ wk,
    const float* __restrict__ bk, const float* __restrict__ wv,
    const float* __restrict__ bv, u16* __restrict__ q, u16* __restrict__ k,
    u16* __restrict__ v) {
  const int z = blockIdx.z;
  const float* W = z == 0 ? wq : (z == 1 ? wk : wv);
  const float* bias = z == 0 ? bq : (z == 1 ? bk : bv);
  u16* C = z == 0 ? q : (z == 1 ? k : v);
  gemm_body<0, 0>(x, W, bias, C, D_);
}

// ---- grouped QKV GEMM (fallback): weight rows [g*512, g*512+512)
__global__ __launch_bounds__(256) void k_gemm_qkv_g(
    const float* __restrict__ x, const float* __restrict__ wq,
    const float* __restrict__ bq, const float* __restrict__ wk,
    const float* __restrict__ bk, const float* __restrict__ wv,
    const float* __restrict__ bv, u16* __restrict__ qg, u16* __restrict__ kg,
    u16* __restrict__ vg, int g) {
  const int z = blockIdx.z;
  const float* W = (z == 0 ? wq : (z == 1 ? wk : wv)) + (size_t)g * GW * D_;
  const float* bias = (z == 0 ? bq : (z == 1 ? bk : bv)) + g * GW;
  u16* C = z == 0 ? qg : (z == 1 ? kg : vg);
  gemm_body<0, 0>(x, W, bias, C, GW);
}

// Final: out(f32) = ao(bf16) @ wo^T + bo
__global__ __launch_bounds__(256) void k_gemm_out(const u16* __restrict__ ao,
                                                  const float* __restrict__ wo,
                                                  const float* __restrict__ bo,
                                                  float* __restrict__ out) {
  gemm_body<1, 1>(ao, wo, bo, out, D_);
}

// ---------------- RoPE (interleaved) in place, generic row stride / heads
__device__ __forceinline__ void rope_one(u16* p, float cv, float sv) {
  unsigned u = *(const unsigned*)p;
  float x1 = bf2f((u16)(u & 0xffff)), x2 = bf2f((u16)(u >> 16));
  unsigned r = (unsigned)f2bf(x1 * cv - x2 * sv) |
               ((unsigned)f2bf(x1 * sv + x2 * cv) << 16);
  *(unsigned*)p = r;
}

__global__ void k_rope_full(u16* q, u16* kk) {
  const int idx = blockIdx.x * 256 + threadIdx.x;  // B*S*16*64 = 4,194,304
  const int i = idx & 63;
  const int hh = (idx >> 6) & 15;
  const int bs = idx >> 10;
  const int s = bs & (S_ - 1);
  const float freq = expf(-(float)i * 0.14391157f);  // ln(10000)/64
  float sv, cv;
  sincosf((float)s * freq, &sv, &cv);
  const size_t off = (size_t)bs * D_ + (size_t)hh * HD_ + 2 * i;
  rope_one(q + off, cv, sv);
  rope_one(kk + off, cv, sv);
}

__global__ void k_rope_g(u16* q, u16* kk) {
  const int idx = blockIdx.x * 256 + threadIdx.x;  // B*S*4*64 = 1,048,576
  const int i = idx & 63;
  const int hh = (idx >> 6) & 3;
  const int bs = idx >> 8;
  const int s = bs & (S_ - 1);
  const float freq = expf(-(float)i * 0.14391157f);
  float sv, cv;
  sincosf((float)s * freq, &sv, &cv);
  const size_t off = (size_t)bs * GW + (size_t)hh * HD_ + 2 * i;
  rope_one(q + off, cv, sv);
  rope_one(kk + off, cv, sv);
}

// ---------------- Flash attention (causal), all bf16, parameterized strides.
// Q/K/V row stride = ld_in with per-head col offset; O stride ld_out.
// O may alias Q: each block reads only its own (row-tile x head) Q region at
// start and writes O to exactly that region at end; regions are disjoint
// across blocks.
__device__ __forceinline__ void attn_body(const u16* Q, const u16* Kd,
                                          const u16* V, u16* O,
                                          size_t base_in, size_t base_out,
                                          int ld_in, int ld_out) {
  const int q0 = blockIdx.x * 64;
  const int t = threadIdx.x, w = t >> 6, l = t & 63, lr = l & 15, lg = l >> 4;

  __shared__ u16 Ks[KB * HD_];       // [32][128], chunk-XOR swizzled
  __shared__ u16 Vt[HD_ * VSTRIDE];  // transposed [128][40-padded]
  __shared__ u16 Ps[4][16 * KB];     // per-wave P tile

  bf16x8 qf[4];
  {
    const u16* qp = Q + base_in + (size_t)(q0 + w * 16 + lr) * ld_in;
#pragma unroll
    for (int ds = 0; ds < 4; ++ds)
      qf[ds] = *(const bf16x8*)(qp + ds * 32 + lg * 8);
  }

  f32x4 oacc[8];
#pragma unroll
  for (int f = 0; f < 8; ++f) oacc[f] = f32x4{0.f, 0.f, 0.f, 0.f};
  float mrow[4] = {-1e30f, -1e30f, -1e30f, -1e30f};
  float lrow[4] = {0.f, 0.f, 0.f, 0.f};

  const int q_hi = q0 + w * 16 + 15;
  const int ntiles = (q0 + 64) / KB;
  const float sc = 0.08838834764831845f;  // 1/sqrt(128)

  for (int tkv = 0; tkv < ntiles; ++tkv) {
    const int kv0 = tkv * KB;
#pragma unroll
    for (int r = 0; r < 2; ++r) {
      const int c = t + 256 * r;
      const int row = c >> 4, c16 = c & 15;
      const int gc = c16 ^ (row & 7);
      gload16(Kd + base_in + (size_t)(kv0 + row) * ld_in + gc * 8,
              (char*)Ks + (size_t)(w + 4 * r) * 1024);
    }
#pragma unroll
    for (int r = 0; r < 2; ++r) {
      const int c = t + 256 * r;
      const int kk = c & 31, d0 = (c >> 5) * 8;
      bf16x8 vv = *(const bf16x8*)(V + base_in + (size_t)(kv0 + kk) * ld_in + d0);
#pragma unroll
      for (int j = 0; j < 8; ++j) Vt[(size_t)(d0 + j) * VSTRIDE + kk] = (u16)vv[j];
    }
    __syncthreads();

    if (kv0 <= q_hi) {
      f32x4 s0 = {0.f, 0.f, 0.f, 0.f}, s1 = {0.f, 0.f, 0.f, 0.f};
#pragma unroll
      for (int ds = 0; ds < 4; ++ds) {
        const int ch = (ds * 4 + lg) ^ (lr & 7);
        bf16x8 k0 = *(const bf16x8*)(Ks + (size_t)lr * HD_ + ch * 8);
        bf16x8 k1 = *(const bf16x8*)(Ks + (size_t)(16 + lr) * HD_ + ch * 8);
        s0 = mfma16(qf[ds], k0, s0);
        s1 = mfma16(qf[ds], k1, s1);
      }
      float p0[4], p1[4], pmax[4];
#pragma unroll
      for (int j = 0; j < 4; ++j) {
        const int qrow = q0 + w * 16 + lg * 4 + j;
        float a0 = s0[j] * sc;
        if (kv0 + lr > qrow) a0 = -1e30f;
        float a1 = s1[j] * sc;
        if (kv0 + 16 + lr > qrow) a1 = -1e30f;
        p0[j] = a0;
        p1[j] = a1;
        pmax[j] = fmaxf(a0, a1);
      }
#pragma unroll
      for (int mk = 1; mk <= 8; mk <<= 1)
#pragma unroll
        for (int j = 0; j < 4; ++j)
          pmax[j] = fmaxf(pmax[j], __shfl_xor(pmax[j], mk, 64));
      float scl[4], rsum[4];
#pragma unroll
      for (int j = 0; j < 4; ++j) {
        const float mn = fmaxf(mrow[j], pmax[j]);
        scl[j] = __expf(mrow[j] - mn);
        mrow[j] = mn;
        const float e0 = __expf(p0[j] - mn);
        const float e1 = __expf(p1[j] - mn);
        p0[j] = e0;
        p1[j] = e1;
        rsum[j] = e0 + e1;
      }
#pragma unroll
      for (int mk = 1; mk <= 8; mk <<= 1)
#pragma unroll
        for (int j = 0; j < 4; ++j) rsum[j] += __shfl_xor(rsum[j], mk, 64);
#pragma unroll
      for (int j = 0; j < 4; ++j) lrow[j] = lrow[j] * scl[j] + rsum[j];
#pragma unroll
      for (int f = 0; f < 8; ++f)
#pragma unroll
        for (int j = 0; j < 4; ++j) oacc[f][j] *= scl[j];
#pragma unroll
      for (int j = 0; j < 4; ++j) {
        const int prow = lg * 4 + j;
        Ps[w][prow * KB + lr] = f2bf(p0[j]);
        Ps[w][prow * KB + 16 + lr] = f2bf(p1[j]);
      }
      bf16x8 pf = *(const bf16x8*)(&Ps[w][lr * KB + lg * 8]);
#pragma unroll
      for (int f = 0; f < 8; ++f) {
        bf16x8 vf = *(const bf16x8*)(Vt + (size_t)(f * 16 + lr) * VSTRIDE + lg * 8);
        oacc[f] = mfma16(pf, vf, oacc[f]);
      }
    }
    __syncthreads();
  }

  float inv[4];
#pragma unroll
  for (int j = 0; j < 4; ++j) inv[j] = 1.0f / lrow[j];
  u16* Op = O + base_out;
#pragma unroll
  for (int f = 0; f < 8; ++f)
#pragma unroll
    for (int j = 0; j < 4; ++j)
      Op[(size_t)(q0 + w * 16 + lg * 4 + j) * ld_out + f * 16 + lr] =
          f2bf(oacc[f][j] * inv[j]);
}

// merged: all 16 heads, grid (32, 32); O aliases Q (in-place safe, see above)
__global__ __launch_bounds__(256) void k_attn_full(const u16* Q, const u16* Kd,
                                                   const u16* V, u16* O) {
  const int by = blockIdx.y;
  const int b = by >> 4, h = by & 15;
  const size_t base = ((size_t)b * S_) * D_ + (size_t)h * HD_;
  attn_body(Q, Kd, V, O, base, base, D_, D_);
}

// grouped fallback: 4 heads, compact stride GW in, full stride out
__global__ __launch_bounds__(256) void k_attn_g(const u16* __restrict__ Q,
                                                const u16* __restrict__ Kd,
                                                const u16* __restrict__ V,
                                                u16* __restrict__ O, int g) {
  const int by = blockIdx.y;
  const int b = by >> 2, hh = by & 3;
  const size_t base_in = ((size_t)b * S_) * GW + (size_t)hh * HD_;
  const size_t base_out = ((size_t)b * S_) * D_ + (size_t)(g * 4 + hh) * HD_;
  attn_body(Q, Kd, V, O, base_in, base_out, GW, D_);
}

extern "C" void kernel_launch(void* const* d_in, const int* in_sizes, int n_in,
                              void* d_out, int out_size, void* d_ws,
                              size_t ws_size, hipStream_t stream) {
  (void)in_sizes; (void)n_in; (void)out_size;
  const float* x = (const float*)d_in[0];
  const float* wq = (const float*)d_in[1];
  const float* bq = (const float*)d_in[2];
  const float* wk = (const float*)d_in[3];
  const float* bk = (const float*)d_in[4];
  const float* wv = (const float*)d_in[5];
  const float* bv = (const float*)d_in[6];
  const float* wo = (const float*)d_in[7];
  const float* bo = (const float*)d_in[8];
  float* out = (float*)d_out;

  const size_t BUF = (size_t)B_ * S_ * D_ * 2;  // one bf16 [4096,2048] = 16.77 MB

  if (ws_size >= 2 * BUF) {
    // Merged path. q,k in ws; v in ws (if it fits) else in d_out (v is dead
    // before the final GEMM overwrites d_out). ao aliases q.
    u16* q = (u16*)d_ws;
    u16* k = q + BUF / 2;
    u16* v = (ws_size >= 3 * BUF) ? (k + BUF / 2) : (u16*)d_out;
    u16* ao = q;

    dim3 g1(16, 32, 3);
    k_gemm_qkv_full<<<g1, 256, 0, stream>>>(x, wq, bq, wk, bk, wv, bv, q, k, v);
    k_rope_full<<<16384, 256, 0, stream>>>(q, k);
    dim3 g2(32, 32);
    k_attn_full<<<g2, 256, 0, stream>>>(q, k, v, ao);
    dim3 g3(16, 32);
    k_gemm_out<<<g3, 256, 0, stream>>>(ao, wo, bo, out);
  } else {
    // Proven R5 grouped fallback: ao (16.77 MB) in ws; compact q/k/v in d_out.
    u16* qg = (u16*)d_out;
    u16* kg = qg + (size_t)(B_ * S_) * GW;
    u16* vg = kg + (size_t)(B_ * S_) * GW;
    u16* ao = (u16*)d_ws;

    for (int g = 0; g < 4; ++g) {
      dim3 g1(4, 32, 3);
      k_gemm_qkv_g<<<g1, 256, 0, stream>>>(x, wq, bq, wk, bk, wv, bv, qg, kg, vg, g);
      k_rope_g<<<4096, 256, 0, stream>>>(qg, kg);
      dim3 g2(32, 8);
      k_attn_g<<<g2, 256, 0, stream>>>(qg, kg, vg, ao, g);
    }
    dim3 g3(16, 32);
    k_gemm_out<<<g3, 256, 0, stream>>>(ao, wo, bo, out);
  }
}

// Round 7
// 410.373 us; speedup vs baseline: 2.0475x; 1.2644x over previous
//
#include <hip/hip_runtime.h>

typedef unsigned short u16;
typedef short bf16x8 __attribute__((ext_vector_type(8)));
typedef float f32x4 __attribute__((ext_vector_type(4)));

#define B_ 2
#define S_ 2048
#define D_ 2048
#define HD_ 128
#define GW 512  // head-group width for fallback path
#define KB 32
#define VSTRIDE 40

__device__ __forceinline__ float bf2f(u16 h) {
  unsigned u = ((unsigned)h) << 16;
  return __builtin_bit_cast(float, u);
}
__device__ __forceinline__ u16 f2bf(float f) {
  unsigned u = __builtin_bit_cast(unsigned, f);
  u += 0x7FFF + ((u >> 16) & 1);
  return (u16)(u >> 16);
}
__device__ __forceinline__ bf16x8 cvt8(const float* p) {
  float4 a = *(const float4*)p;
  float4 b = *(const float4*)(p + 4);
  bf16x8 r;
  r[0] = (short)f2bf(a.x); r[1] = (short)f2bf(a.y);
  r[2] = (short)f2bf(a.z); r[3] = (short)f2bf(a.w);
  r[4] = (short)f2bf(b.x); r[5] = (short)f2bf(b.y);
  r[6] = (short)f2bf(b.z); r[7] = (short)f2bf(b.w);
  return r;
}

__device__ __forceinline__ void gload16(const void* g, void* lds) {
  __builtin_amdgcn_global_load_lds(
      (const __attribute__((address_space(1))) unsigned*)g,
      (__attribute__((address_space(3))) unsigned*)lds, 16, 0, 0);
}

__device__ __forceinline__ f32x4 mfma16(bf16x8 a, bf16x8 b, f32x4 c) {
  return __builtin_amdgcn_mfma_f32_16x16x32_bf16(a, b, c, 0, 0, 0);
}

// ---------------- GEMM: C = A(M,2048) @ W(N,2048)^T + bias
// A: f32 (AM=0, reg-stage+cvt) or bf16 (AM=1, global_load_lds).
// W: f32 always (reg-stage+cvt). C: bf16 (CM=0) or f32 (CM=1), row stride ldc.
// 128x128 tile, BK=32, 4 waves (2x2), 16x16x32 MFMA (m97 structure).
template <int AM, int CM>
__device__ __forceinline__ void gemm_body(const void* Ap, const float* __restrict__ W,
                                          const float* __restrict__ bias,
                                          void* Cp, int ldc) {
  constexpr int K = 2048;
  __shared__ u16 As[128 * 32];
  __shared__ u16 Bs[128 * 32];
  const int t = threadIdx.x;
  const int w = t >> 6, l = t & 63, lr = l & 15, lg = l >> 4;
  const int m0 = blockIdx.y * 128, n0 = blockIdx.x * 128;
  const int wr = w >> 1, wc = w & 1;

  f32x4 acc[4][4];
#pragma unroll
  for (int i = 0; i < 4; ++i)
#pragma unroll
    for (int j = 0; j < 4; ++j) acc[i][j] = f32x4{0.f, 0.f, 0.f, 0.f};

  const int rowA0 = t >> 2, ko0 = (t & 3) * 8;
  const int rowA1 = (t + 256) >> 2, ko1 = ((t + 256) & 3) * 8;

  for (int kt = 0; kt < K; kt += 32) {
    if constexpr (AM == 1) {
      const u16* A = (const u16*)Ap;
      gload16(A + (size_t)(m0 + rowA0) * K + kt + ko0, (char*)As + (size_t)w * 1024);
      gload16(A + (size_t)(m0 + rowA1) * K + kt + ko1, (char*)As + (size_t)(w + 4) * 1024);
    } else {
      const float* A = (const float*)Ap;
      *(bf16x8*)((char*)As + (size_t)t * 16) = cvt8(A + (size_t)(m0 + rowA0) * K + kt + ko0);
      *(bf16x8*)((char*)As + (size_t)(t + 256) * 16) = cvt8(A + (size_t)(m0 + rowA1) * K + kt + ko1);
    }
    *(bf16x8*)((char*)Bs + (size_t)t * 16) = cvt8(W + (size_t)(n0 + rowA0) * K + kt + ko0);
    *(bf16x8*)((char*)Bs + (size_t)(t + 256) * 16) = cvt8(W + (size_t)(n0 + rowA1) * K + kt + ko1);
    __syncthreads();

    bf16x8 af[4], bw[4];
#pragma unroll
    for (int i = 0; i < 4; ++i) {
      af[i] = *(const bf16x8*)(As + (size_t)(wr * 64 + i * 16 + lr) * 32 + lg * 8);
      bw[i] = *(const bf16x8*)(Bs + (size_t)(wc * 64 + i * 16 + lr) * 32 + lg * 8);
    }
#pragma unroll
    for (int i = 0; i < 4; ++i)
#pragma unroll
      for (int j = 0; j < 4; ++j)
        acc[i][j] = mfma16(af[i], bw[j], acc[i][j]);
    __syncthreads();
  }

#pragma unroll
  for (int i = 0; i < 4; ++i) {
#pragma unroll
    for (int j = 0; j < 4; ++j) {
      const int col = n0 + wc * 64 + j * 16 + lr;
      const float bv = bias[col];
      const int row = m0 + wr * 64 + i * 16 + lg * 4;
#pragma unroll
      for (int r = 0; r < 4; ++r) {
        if constexpr (CM == 1)
          ((float*)Cp)[(size_t)(row + r) * ldc + col] = acc[i][j][r] + bv;
        else
          ((u16*)Cp)[(size_t)(row + r) * ldc + col] = f2bf(acc[i][j][r] + bv);
      }
    }
  }
}

// ---- merged QKV GEMM: full [4096,2048] bf16 outputs, grid (16,32,3)
__global__ __launch_bounds__(256) void k_gemm_qkv_full(
    const float* __restrict__ x, const float* __restrict__ wq,
    const float* __restrict__ bq, const float* __restrict__ wk,
    const float* __restrict__ bk, const float* __restrict__ wv,
    const float* __restrict__ bv, u16* __restrict__ q, u16* __restrict__ k,
    u16* __restrict__ v) {
  const int z = blockIdx.z;
  const float* W = z == 0 ? wq : (z == 1 ? wk : wv);
  const float* bias = z == 0 ? bq : (z == 1 ? bk : bv);
  u16* C = z == 0 ? q : (z == 1 ? k : v);
  gemm_body<0, 0>(x, W, bias, C, D_);
}

// ---- grouped QKV GEMM (fallback): weight rows [g*512, g*512+512)
__global__ __launch_bounds__(256) void k_gemm_qkv_g(
    const float* __restrict__ x, const float* __restrict__ wq,
    const float* __restrict__ bq, const float* __restrict__ wk,
    const float* __restrict__ bk, const float* __restrict__ wv,
    const float* __restrict__ bv, u16* __restrict__ qg, u16* __restrict__ kg,
    u16* __restrict__ vg, int g) {
  const int z = blockIdx.z;
  const float* W = (z == 0 ? wq : (z == 1 ? wk : wv)) + (size_t)g * GW * D_;
  const float* bias = (z == 0 ? bq : (z == 1 ? bk : bv)) + g * GW;
  u16* C = z == 0 ? qg : (z == 1 ? kg : vg);
  gemm_body<0, 0>(x, W, bias, C, GW);
}

// Final: out(f32) = ao(bf16) @ wo^T + bo
__global__ __launch_bounds__(256) void k_gemm_out(const u16* __restrict__ ao,
                                                  const float* __restrict__ wo,
                                                  const float* __restrict__ bo,
                                                  float* __restrict__ out) {
  gemm_body<1, 1>(ao, wo, bo, out, D_);
}

// ---------------- RoPE (interleaved) in place, generic row stride / heads
__device__ __forceinline__ void rope_one(u16* p, float cv, float sv) {
  unsigned u = *(const unsigned*)p;
  float x1 = bf2f((u16)(u & 0xffff)), x2 = bf2f((u16)(u >> 16));
  unsigned r = (unsigned)f2bf(x1 * cv - x2 * sv) |
               ((unsigned)f2bf(x1 * sv + x2 * cv) << 16);
  *(unsigned*)p = r;
}

__global__ void k_rope_full(u16* q, u16* kk) {
  const int idx = blockIdx.x * 256 + threadIdx.x;  // B*S*16*64 = 4,194,304
  const int i = idx & 63;
  const int hh = (idx >> 6) & 15;
  const int bs = idx >> 10;
  const int s = bs & (S_ - 1);
  const float freq = expf(-(float)i * 0.14391157f);  // ln(10000)/64
  float sv, cv;
  sincosf((float)s * freq, &sv, &cv);
  const size_t off = (size_t)bs * D_ + (size_t)hh * HD_ + 2 * i;
  rope_one(q + off, cv, sv);
  rope_one(kk + off, cv, sv);
}

__global__ void k_rope_g(u16* q, u16* kk) {
  const int idx = blockIdx.x * 256 + threadIdx.x;  // B*S*4*64 = 1,048,576
  const int i = idx & 63;
  const int hh = (idx >> 6) & 3;
  const int bs = idx >> 8;
  const int s = bs & (S_ - 1);
  const float freq = expf(-(float)i * 0.14391157f);
  float sv, cv;
  sincosf((float)s * freq, &sv, &cv);
  const size_t off = (size_t)bs * GW + (size_t)hh * HD_ + 2 * i;
  rope_one(q + off, cv, sv);
  rope_one(kk + off, cv, sv);
}

// ---------------- Flash attention (causal), all bf16, parameterized strides.
// Processes the 64-row q-tile starting at q0. O may alias Q: each call reads
// only its own (q-tile x head) Q region at start and writes O to exactly that
// region at end; regions are disjoint across blocks and across paired calls.
__device__ __forceinline__ void attn_body(const u16* Q, const u16* Kd,
                                          const u16* V, u16* O,
                                          size_t base_in, size_t base_out,
                                          int ld_in, int ld_out, int q0) {
  const int t = threadIdx.x, w = t >> 6, l = t & 63, lr = l & 15, lg = l >> 4;

  __shared__ u16 Ks[KB * HD_];       // [32][128], chunk-XOR swizzled
  __shared__ u16 Vt[HD_ * VSTRIDE];  // transposed [128][40-padded]
  __shared__ u16 Ps[4][16 * KB];     // per-wave P tile

  bf16x8 qf[4];
  {
    const u16* qp = Q + base_in + (size_t)(q0 + w * 16 + lr) * ld_in;
#pragma unroll
    for (int ds = 0; ds < 4; ++ds)
      qf[ds] = *(const bf16x8*)(qp + ds * 32 + lg * 8);
  }

  f32x4 oacc[8];
#pragma unroll
  for (int f = 0; f < 8; ++f) oacc[f] = f32x4{0.f, 0.f, 0.f, 0.f};
  float mrow[4] = {-1e30f, -1e30f, -1e30f, -1e30f};
  float lrow[4] = {0.f, 0.f, 0.f, 0.f};

  const int q_hi = q0 + w * 16 + 15;
  const int ntiles = (q0 + 64) / KB;
  const float sc = 0.08838834764831845f;  // 1/sqrt(128)

  for (int tkv = 0; tkv < ntiles; ++tkv) {
    const int kv0 = tkv * KB;
#pragma unroll
    for (int r = 0; r < 2; ++r) {
      const int c = t + 256 * r;
      const int row = c >> 4, c16 = c & 15;
      const int gc = c16 ^ (row & 7);
      gload16(Kd + base_in + (size_t)(kv0 + row) * ld_in + gc * 8,
              (char*)Ks + (size_t)(w + 4 * r) * 1024);
    }
#pragma unroll
    for (int r = 0; r < 2; ++r) {
      const int c = t + 256 * r;
      const int kk = c & 31, d0 = (c >> 5) * 8;
      bf16x8 vv = *(const bf16x8*)(V + base_in + (size_t)(kv0 + kk) * ld_in + d0);
#pragma unroll
      for (int j = 0; j < 8; ++j) Vt[(size_t)(d0 + j) * VSTRIDE + kk] = (u16)vv[j];
    }
    __syncthreads();

    if (kv0 <= q_hi) {
      f32x4 s0 = {0.f, 0.f, 0.f, 0.f}, s1 = {0.f, 0.f, 0.f, 0.f};
#pragma unroll
      for (int ds = 0; ds < 4; ++ds) {
        const int ch = (ds * 4 + lg) ^ (lr & 7);
        bf16x8 k0 = *(const bf16x8*)(Ks + (size_t)lr * HD_ + ch * 8);
        bf16x8 k1 = *(const bf16x8*)(Ks + (size_t)(16 + lr) * HD_ + ch * 8);
        s0 = mfma16(qf[ds], k0, s0);
        s1 = mfma16(qf[ds], k1, s1);
      }
      float p0[4], p1[4], pmax[4];
#pragma unroll
      for (int j = 0; j < 4; ++j) {
        const int qrow = q0 + w * 16 + lg * 4 + j;
        float a0 = s0[j] * sc;
        if (kv0 + lr > qrow) a0 = -1e30f;
        float a1 = s1[j] * sc;
        if (kv0 + 16 + lr > qrow) a1 = -1e30f;
        p0[j] = a0;
        p1[j] = a1;
        pmax[j] = fmaxf(a0, a1);
      }
#pragma unroll
      for (int mk = 1; mk <= 8; mk <<= 1)
#pragma unroll
        for (int j = 0; j < 4; ++j)
          pmax[j] = fmaxf(pmax[j], __shfl_xor(pmax[j], mk, 64));
      float scl[4], rsum[4];
#pragma unroll
      for (int j = 0; j < 4; ++j) {
        const float mn = fmaxf(mrow[j], pmax[j]);
        scl[j] = __expf(mrow[j] - mn);
        mrow[j] = mn;
        const float e0 = __expf(p0[j] - mn);
        const float e1 = __expf(p1[j] - mn);
        p0[j] = e0;
        p1[j] = e1;
        rsum[j] = e0 + e1;
      }
#pragma unroll
      for (int mk = 1; mk <= 8; mk <<= 1)
#pragma unroll
        for (int j = 0; j < 4; ++j) rsum[j] += __shfl_xor(rsum[j], mk, 64);
#pragma unroll
      for (int j = 0; j < 4; ++j) lrow[j] = lrow[j] * scl[j] + rsum[j];
#pragma unroll
      for (int f = 0; f < 8; ++f)
#pragma unroll
        for (int j = 0; j < 4; ++j) oacc[f][j] *= scl[j];
#pragma unroll
      for (int j = 0; j < 4; ++j) {
        const int prow = lg * 4 + j;
        Ps[w][prow * KB + lr] = f2bf(p0[j]);
        Ps[w][prow * KB + 16 + lr] = f2bf(p1[j]);
      }
      bf16x8 pf = *(const bf16x8*)(&Ps[w][lr * KB + lg * 8]);
#pragma unroll
      for (int f = 0; f < 8; ++f) {
        bf16x8 vf = *(const bf16x8*)(Vt + (size_t)(f * 16 + lr) * VSTRIDE + lg * 8);
        oacc[f] = mfma16(pf, vf, oacc[f]);
      }
    }
    __syncthreads();
  }

  float inv[4];
#pragma unroll
  for (int j = 0; j < 4; ++j) inv[j] = 1.0f / lrow[j];
  u16* Op = O + base_out;
#pragma unroll
  for (int f = 0; f < 8; ++f)
#pragma unroll
    for (int j = 0; j < 4; ++j)
      Op[(size_t)(q0 + w * 16 + lg * 4 + j) * ld_out + f * 16 + lr] =
          f2bf(oacc[f][j] * inv[j]);
}

// merged, triangular-paired: 512 blocks; each does q-tiles (31-pr) and pr of
// one (b,h) -> uniform 66 KV iterations per block regardless of dispatch order.
// XCD-chunked remap: blocks resident on one XCD process 4 consecutive heads
// (4MB K/V ~= one XCD L2). O aliases Q (disjoint row regions, see attn_body).
__global__ __launch_bounds__(256) void k_attn_full(const u16* Q, const u16* Kd,
                                                   const u16* V, u16* O) {
  const int lin = blockIdx.y * gridDim.x + blockIdx.x;  // grid (16, 32) = 512
  const int work = (lin & 7) * 64 + (lin >> 3);         // bijective XCD chunking
  const int bh = work >> 4;  // 0..31
  const int pr = work & 15;  // 0..15
  const int b = bh >> 4, h = bh & 15;
  const size_t base = ((size_t)b * S_) * D_ + (size_t)h * HD_;
  attn_body(Q, Kd, V, O, base, base, D_, D_, 64 * (31 - pr));
  attn_body(Q, Kd, V, O, base, base, D_, D_, 64 * pr);
}

// grouped fallback: 4 heads, compact stride GW in, full stride out
__global__ __launch_bounds__(256) void k_attn_g(const u16* __restrict__ Q,
                                                const u16* __restrict__ Kd,
                                                const u16* __restrict__ V,
                                                u16* __restrict__ O, int g) {
  const int by = blockIdx.y;
  const int b = by >> 2, hh = by & 3;
  const size_t base_in = ((size_t)b * S_) * GW + (size_t)hh * HD_;
  const size_t base_out = ((size_t)b * S_) * D_ + (size_t)(g * 4 + hh) * HD_;
  attn_body(Q, Kd, V, O, base_in, base_out, GW, D_, blockIdx.x * 64);
}

extern "C" void kernel_launch(void* const* d_in, const int* in_sizes, int n_in,
                              void* d_out, int out_size, void* d_ws,
                              size_t ws_size, hipStream_t stream) {
  (void)in_sizes; (void)n_in; (void)out_size;
  const float* x = (const float*)d_in[0];
  const float* wq = (const float*)d_in[1];
  const float* bq = (const float*)d_in[2];
  const float* wk = (const float*)d_in[3];
  const float* bk = (const float*)d_in[4];
  const float* wv = (const float*)d_in[5];
  const float* bv = (const float*)d_in[6];
  const float* wo = (const float*)d_in[7];
  const float* bo = (const float*)d_in[8];
  float* out = (float*)d_out;

  const size_t BUF = (size_t)B_ * S_ * D_ * 2;  // one bf16 [4096,2048] = 16.77 MB

  if (ws_size >= 2 * BUF) {
    // Merged path. q,k in ws; v in ws (if it fits) else in d_out (v is dead
    // before the final GEMM overwrites d_out). ao aliases q.
    u16* q = (u16*)d_ws;
    u16* k = q + BUF / 2;
    u16* v = (ws_size >= 3 * BUF) ? (k + BUF / 2) : (u16*)d_out;
    u16* ao = q;

    dim3 g1(16, 32, 3);
    k_gemm_qkv_full<<<g1, 256, 0, stream>>>(x, wq, bq, wk, bk, wv, bv, q, k, v);
    k_rope_full<<<16384, 256, 0, stream>>>(q, k);
    dim3 g2(16, 32);
    k_attn_full<<<g2, 256, 0, stream>>>(q, k, v, ao);
    dim3 g3(16, 32);
    k_gemm_out<<<g3, 256, 0, stream>>>(ao, wo, bo, out);
  } else {
    // Proven R5 grouped fallback: ao (16.77 MB) in ws; compact q/k/v in d_out.
    u16* qg = (u16*)d_out;
    u16* kg = qg + (size_t)(B_ * S_) * GW;
    u16* vg = kg + (size_t)(B_ * S_) * GW;
    u16* ao = (u16*)d_ws;

    for (int g = 0; g < 4; ++g) {
      dim3 g1(4, 32, 3);
      k_gemm_qkv_g<<<g1, 256, 0, stream>>>(x, wq, bq, wk, bk, wv, bv, qg, kg, vg, g);
      k_rope_g<<<4096, 256, 0, stream>>>(qg, kg);
      dim3 g2(32, 8);
      k_attn_g<<<g2, 256, 0, stream>>>(qg, kg, vg, ao, g);
    }
    dim3 g3(16, 32);
    k_gemm_out<<<g3, 256, 0, stream>>>(ao, wo, bo, out);
  }
}

// Round 8
// 340.342 us; speedup vs baseline: 2.4687x; 1.2058x over previous
//
#include <hip/hip_runtime.h>

typedef unsigned short u16;
typedef short bf16x8 __attribute__((ext_vector_type(8)));
typedef float f32x4 __attribute__((ext_vector_type(4)));

#define B_ 2
#define S_ 2048
#define D_ 2048
#define HD_ 128
#define GW 512  // head-group width for fallback path
#define KB 32
#define VSTRIDE 40

__device__ __forceinline__ float bf2f(u16 h) {
  unsigned u = ((unsigned)h) << 16;
  return __builtin_bit_cast(float, u);
}
__device__ __forceinline__ u16 f2bf(float f) {
  unsigned u = __builtin_bit_cast(unsigned, f);
  u += 0x7FFF + ((u >> 16) & 1);
  return (u16)(u >> 16);
}
__device__ __forceinline__ bf16x8 cvt8(const float* p) {
  float4 a = *(const float4*)p;
  float4 b = *(const float4*)(p + 4);
  bf16x8 r;
  r[0] = (short)f2bf(a.x); r[1] = (short)f2bf(a.y);
  r[2] = (short)f2bf(a.z); r[3] = (short)f2bf(a.w);
  r[4] = (short)f2bf(b.x); r[5] = (short)f2bf(b.y);
  r[6] = (short)f2bf(b.z); r[7] = (short)f2bf(b.w);
  return r;
}

__device__ __forceinline__ void gload16(const void* g, void* lds) {
  __builtin_amdgcn_global_load_lds(
      (const __attribute__((address_space(1))) unsigned*)g,
      (__attribute__((address_space(3))) unsigned*)lds, 16, 0, 0);
}

__device__ __forceinline__ f32x4 mfma16(bf16x8 a, bf16x8 b, f32x4 c) {
  return __builtin_amdgcn_mfma_f32_16x16x32_bf16(a, b, c, 0, 0, 0);
}

// ---------------- f32 -> bf16 bulk convert. Grid (4096, nslices).
// slice 0: x (1,048,576 x8); 1..3: wq/wk/wv -> wqkvb stacked; 4: wo -> wob.
__global__ void k_cvt_all(const float* __restrict__ x, const float* __restrict__ wq,
                          const float* __restrict__ wk, const float* __restrict__ wv,
                          const float* __restrict__ wo, u16* __restrict__ xb,
                          u16* __restrict__ wqkvb, u16* __restrict__ wob) {
  const int slice = blockIdx.y;
  const int i = blockIdx.x * 256 + threadIdx.x;
  const float* src;
  u16* dst;
  int n8;
  if (slice == 0) { src = x; dst = xb; n8 = 1048576; }
  else if (slice == 1) { src = wq; dst = wqkvb; n8 = 524288; }
  else if (slice == 2) { src = wk; dst = wqkvb + 4194304; n8 = 524288; }
  else if (slice == 3) { src = wv; dst = wqkvb + 8388608; n8 = 524288; }
  else { src = wo; dst = wob; n8 = 524288; }
  if (i < n8) *(bf16x8*)(dst + (size_t)i * 8) = cvt8(src + (size_t)i * 8);
}

// ---------------- GEMM: C = A(M,2048) @ W(N,2048)^T + bias
// AM/WM: 1 = bf16 via global_load_lds, 0 = f32 reg-stage+cvt.
// CM: 0 = bf16 out, 1 = f32 out. 128x128 tile, BK=32, 4 waves (m97 structure).
template <int AM, int WM, int CM>
__device__ __forceinline__ void gemm_body(const void* Ap, const void* Wp,
                                          const float* __restrict__ bias,
                                          void* Cp, int ldc) {
  constexpr int K = 2048;
  __shared__ u16 As[128 * 32];
  __shared__ u16 Bs[128 * 32];
  const int t = threadIdx.x;
  const int w = t >> 6, l = t & 63, lr = l & 15, lg = l >> 4;
  const int m0 = blockIdx.y * 128, n0 = blockIdx.x * 128;
  const int wr = w >> 1, wc = w & 1;

  f32x4 acc[4][4];
#pragma unroll
  for (int i = 0; i < 4; ++i)
#pragma unroll
    for (int j = 0; j < 4; ++j) acc[i][j] = f32x4{0.f, 0.f, 0.f, 0.f};

  const int rowA0 = t >> 2, ko0 = (t & 3) * 8;
  const int rowA1 = (t + 256) >> 2, ko1 = ((t + 256) & 3) * 8;

  for (int kt = 0; kt < K; kt += 32) {
    if constexpr (AM == 1) {
      const u16* A = (const u16*)Ap;
      gload16(A + (size_t)(m0 + rowA0) * K + kt + ko0, (char*)As + (size_t)w * 1024);
      gload16(A + (size_t)(m0 + rowA1) * K + kt + ko1, (char*)As + (size_t)(w + 4) * 1024);
    } else {
      const float* A = (const float*)Ap;
      *(bf16x8*)((char*)As + (size_t)t * 16) = cvt8(A + (size_t)(m0 + rowA0) * K + kt + ko0);
      *(bf16x8*)((char*)As + (size_t)(t + 256) * 16) = cvt8(A + (size_t)(m0 + rowA1) * K + kt + ko1);
    }
    if constexpr (WM == 1) {
      const u16* W = (const u16*)Wp;
      gload16(W + (size_t)(n0 + rowA0) * K + kt + ko0, (char*)Bs + (size_t)w * 1024);
      gload16(W + (size_t)(n0 + rowA1) * K + kt + ko1, (char*)Bs + (size_t)(w + 4) * 1024);
    } else {
      const float* W = (const float*)Wp;
      *(bf16x8*)((char*)Bs + (size_t)t * 16) = cvt8(W + (size_t)(n0 + rowA0) * K + kt + ko0);
      *(bf16x8*)((char*)Bs + (size_t)(t + 256) * 16) = cvt8(W + (size_t)(n0 + rowA1) * K + kt + ko1);
    }
    __syncthreads();

    bf16x8 af[4], bw[4];
#pragma unroll
    for (int i = 0; i < 4; ++i) {
      af[i] = *(const bf16x8*)(As + (size_t)(wr * 64 + i * 16 + lr) * 32 + lg * 8);
      bw[i] = *(const bf16x8*)(Bs + (size_t)(wc * 64 + i * 16 + lr) * 32 + lg * 8);
    }
#pragma unroll
    for (int i = 0; i < 4; ++i)
#pragma unroll
      for (int j = 0; j < 4; ++j)
        acc[i][j] = mfma16(af[i], bw[j], acc[i][j]);
    __syncthreads();
  }

#pragma unroll
  for (int i = 0; i < 4; ++i) {
#pragma unroll
    for (int j = 0; j < 4; ++j) {
      const int col = n0 + wc * 64 + j * 16 + lr;
      const float bv = bias[col];
      const int row = m0 + wr * 64 + i * 16 + lg * 4;
#pragma unroll
      for (int r = 0; r < 4; ++r) {
        if constexpr (CM == 1)
          ((float*)Cp)[(size_t)(row + r) * ldc + col] = acc[i][j][r] + bv;
        else
          ((u16*)Cp)[(size_t)(row + r) * ldc + col] = f2bf(acc[i][j][r] + bv);
      }
    }
  }
}

// ---- tier 1: all-bf16 QKV (wqkvb stacked [3][2048][2048]), grid (16,32,3)
__global__ __launch_bounds__(256) void k_gemm_qkv_bb(
    const u16* __restrict__ xb, const u16* __restrict__ wqkvb,
    const float* __restrict__ bq, const float* __restrict__ bk,
    const float* __restrict__ bv, u16* __restrict__ q, u16* __restrict__ k,
    u16* __restrict__ v) {
  const int z = blockIdx.z;
  const u16* W = wqkvb + (size_t)z * D_ * D_;
  const float* bias = z == 0 ? bq : (z == 1 ? bk : bv);
  u16* C = z == 0 ? q : (z == 1 ? k : v);
  gemm_body<1, 1, 0>(xb, W, bias, C, D_);
}

__global__ __launch_bounds__(256) void k_gemm_out_bb(
    const u16* __restrict__ ao, const u16* __restrict__ wob,
    const float* __restrict__ bo, float* __restrict__ out) {
  gemm_body<1, 1, 1>(ao, wob, bo, out, D_);
}

// ---- tier 2: bf16 A, f32 W
__global__ __launch_bounds__(256) void k_gemm_qkv_xb(
    const u16* __restrict__ xb, const float* __restrict__ wq,
    const float* __restrict__ bq, const float* __restrict__ wk,
    const float* __restrict__ bk, const float* __restrict__ wv,
    const float* __restrict__ bv, u16* __restrict__ q, u16* __restrict__ k,
    u16* __restrict__ v) {
  const int z = blockIdx.z;
  const float* W = z == 0 ? wq : (z == 1 ? wk : wv);
  const float* bias = z == 0 ? bq : (z == 1 ? bk : bv);
  u16* C = z == 0 ? q : (z == 1 ? k : v);
  gemm_body<1, 0, 0>(xb, W, bias, C, D_);
}

__global__ __launch_bounds__(256) void k_gemm_out(const u16* __restrict__ ao,
                                                  const float* __restrict__ wo,
                                                  const float* __restrict__ bo,
                                                  float* __restrict__ out) {
  gemm_body<1, 0, 1>(ao, wo, bo, out, D_);
}

// ---- fallback grouped QKV (f32 A, f32 W, compact out)
__global__ __launch_bounds__(256) void k_gemm_qkv_g(
    const float* __restrict__ x, const float* __restrict__ wq,
    const float* __restrict__ bq, const float* __restrict__ wk,
    const float* __restrict__ bk, const float* __restrict__ wv,
    const float* __restrict__ bv, u16* __restrict__ qg, u16* __restrict__ kg,
    u16* __restrict__ vg, int g) {
  const int z = blockIdx.z;
  const float* W = (z == 0 ? wq : (z == 1 ? wk : wv)) + (size_t)g * GW * D_;
  const float* bias = (z == 0 ? bq : (z == 1 ? bk : bv)) + g * GW;
  u16* C = z == 0 ? qg : (z == 1 ? kg : vg);
  gemm_body<0, 0, 0>(x, W, bias, C, GW);
}

// ---------------- RoPE (interleaved) in place
__device__ __forceinline__ void rope_one(u16* p, float cv, float sv) {
  unsigned u = *(const unsigned*)p;
  float x1 = bf2f((u16)(u & 0xffff)), x2 = bf2f((u16)(u >> 16));
  unsigned r = (unsigned)f2bf(x1 * cv - x2 * sv) |
               ((unsigned)f2bf(x1 * sv + x2 * cv) << 16);
  *(unsigned*)p = r;
}

__global__ void k_rope_full(u16* q, u16* kk) {
  const int idx = blockIdx.x * 256 + threadIdx.x;  // B*S*16*64
  const int i = idx & 63;
  const int hh = (idx >> 6) & 15;
  const int bs = idx >> 10;
  const int s = bs & (S_ - 1);
  const float freq = expf(-(float)i * 0.14391157f);  // ln(10000)/64
  float sv, cv;
  sincosf((float)s * freq, &sv, &cv);
  const size_t off = (size_t)bs * D_ + (size_t)hh * HD_ + 2 * i;
  rope_one(q + off, cv, sv);
  rope_one(kk + off, cv, sv);
}

__global__ void k_rope_g(u16* q, u16* kk) {
  const int idx = blockIdx.x * 256 + threadIdx.x;  // B*S*4*64
  const int i = idx & 63;
  const int hh = (idx >> 6) & 3;
  const int bs = idx >> 8;
  const int s = bs & (S_ - 1);
  const float freq = expf(-(float)i * 0.14391157f);
  float sv, cv;
  sincosf((float)s * freq, &sv, &cv);
  const size_t off = (size_t)bs * GW + (size_t)hh * HD_ + 2 * i;
  rope_one(q + off, cv, sv);
  rope_one(kk + off, cv, sv);
}

// ---------------- Flash attention (causal), all bf16, parameterized strides.
// Processes the 64-row q-tile starting at q0. O may alias Q (disjoint regions).
__device__ __forceinline__ void attn_body(const u16* Q, const u16* Kd,
                                          const u16* V, u16* O,
                                          size_t base_in, size_t base_out,
                                          int ld_in, int ld_out, int q0) {
  const int t = threadIdx.x, w = t >> 6, l = t & 63, lr = l & 15, lg = l >> 4;

  __shared__ u16 Ks[KB * HD_];       // [32][128], chunk-XOR swizzled
  __shared__ u16 Vt[HD_ * VSTRIDE];  // transposed [128][40-padded]
  __shared__ u16 Ps[4][16 * KB];     // per-wave P tile

  bf16x8 qf[4];
  {
    const u16* qp = Q + base_in + (size_t)(q0 + w * 16 + lr) * ld_in;
#pragma unroll
    for (int ds = 0; ds < 4; ++ds)
      qf[ds] = *(const bf16x8*)(qp + ds * 32 + lg * 8);
  }

  f32x4 oacc[8];
#pragma unroll
  for (int f = 0; f < 8; ++f) oacc[f] = f32x4{0.f, 0.f, 0.f, 0.f};
  float mrow[4] = {-1e30f, -1e30f, -1e30f, -1e30f};
  float lrow[4] = {0.f, 0.f, 0.f, 0.f};

  const int q_hi = q0 + w * 16 + 15;
  const int ntiles = (q0 + 64) / KB;
  const float sc = 0.08838834764831845f;  // 1/sqrt(128)

  for (int tkv = 0; tkv < ntiles; ++tkv) {
    const int kv0 = tkv * KB;
#pragma unroll
    for (int r = 0; r < 2; ++r) {
      const int c = t + 256 * r;
      const int row = c >> 4, c16 = c & 15;
      const int gc = c16 ^ (row & 7);
      gload16(Kd + base_in + (size_t)(kv0 + row) * ld_in + gc * 8,
              (char*)Ks + (size_t)(w + 4 * r) * 1024);
    }
#pragma unroll
    for (int r = 0; r < 2; ++r) {
      const int c = t + 256 * r;
      const int kk = c & 31, d0 = (c >> 5) * 8;
      bf16x8 vv = *(const bf16x8*)(V + base_in + (size_t)(kv0 + kk) * ld_in + d0);
#pragma unroll
      for (int j = 0; j < 8; ++j) Vt[(size_t)(d0 + j) * VSTRIDE + kk] = (u16)vv[j];
    }
    __syncthreads();

    if (kv0 <= q_hi) {
      f32x4 s0 = {0.f, 0.f, 0.f, 0.f}, s1 = {0.f, 0.f, 0.f, 0.f};
#pragma unroll
      for (int ds = 0; ds < 4; ++ds) {
        const int ch = (ds * 4 + lg) ^ (lr & 7);
        bf16x8 k0 = *(const bf16x8*)(Ks + (size_t)lr * HD_ + ch * 8);
        bf16x8 k1 = *(const bf16x8*)(Ks + (size_t)(16 + lr) * HD_ + ch * 8);
        s0 = mfma16(qf[ds], k0, s0);
        s1 = mfma16(qf[ds], k1, s1);
      }
      float p0[4], p1[4], pmax[4];
#pragma unroll
      for (int j = 0; j < 4; ++j) {
        const int qrow = q0 + w * 16 + lg * 4 + j;
        float a0 = s0[j] * sc;
        if (kv0 + lr > qrow) a0 = -1e30f;
        float a1 = s1[j] * sc;
        if (kv0 + 16 + lr > qrow) a1 = -1e30f;
        p0[j] = a0;
        p1[j] = a1;
        pmax[j] = fmaxf(a0, a1);
      }
#pragma unroll
      for (int mk = 1; mk <= 8; mk <<= 1)
#pragma unroll
        for (int j = 0; j < 4; ++j)
          pmax[j] = fmaxf(pmax[j], __shfl_xor(pmax[j], mk, 64));
      float scl[4], rsum[4];
#pragma unroll
      for (int j = 0; j < 4; ++j) {
        const float mn = fmaxf(mrow[j], pmax[j]);
        scl[j] = __expf(mrow[j] - mn);
        mrow[j] = mn;
        const float e0 = __expf(p0[j] - mn);
        const float e1 = __expf(p1[j] - mn);
        p0[j] = e0;
        p1[j] = e1;
        rsum[j] = e0 + e1;
      }
#pragma unroll
      for (int mk = 1; mk <= 8; mk <<= 1)
#pragma unroll
        for (int j = 0; j < 4; ++j) rsum[j] += __shfl_xor(rsum[j], mk, 64);
#pragma unroll
      for (int j = 0; j < 4; ++j) lrow[j] = lrow[j] * scl[j] + rsum[j];
#pragma unroll
      for (int f = 0; f < 8; ++f)
#pragma unroll
        for (int j = 0; j < 4; ++j) oacc[f][j] *= scl[j];
#pragma unroll
      for (int j = 0; j < 4; ++j) {
        const int prow = lg * 4 + j;
        Ps[w][prow * KB + lr] = f2bf(p0[j]);
        Ps[w][prow * KB + 16 + lr] = f2bf(p1[j]);
      }
      bf16x8 pf = *(const bf16x8*)(&Ps[w][lr * KB + lg * 8]);
#pragma unroll
      for (int f = 0; f < 8; ++f) {
        bf16x8 vf = *(const bf16x8*)(Vt + (size_t)(f * 16 + lr) * VSTRIDE + lg * 8);
        oacc[f] = mfma16(pf, vf, oacc[f]);
      }
    }
    __syncthreads();
  }

  float inv[4];
#pragma unroll
  for (int j = 0; j < 4; ++j) inv[j] = 1.0f / lrow[j];
  u16* Op = O + base_out;
#pragma unroll
  for (int f = 0; f < 8; ++f)
#pragma unroll
    for (int j = 0; j < 4; ++j)
      Op[(size_t)(q0 + w * 16 + lg * 4 + j) * ld_out + f * 16 + lr] =
          f2bf(oacc[f][j] * inv[j]);
}

// merged, triangular-paired: uniform 66 KV iters/block; XCD-chunked remap.
__global__ __launch_bounds__(256) void k_attn_full(const u16* Q, const u16* Kd,
                                                   const u16* V, u16* O) {
  const int lin = blockIdx.y * gridDim.x + blockIdx.x;  // grid (16, 32) = 512
  const int work = (lin & 7) * 64 + (lin >> 3);         // bijective XCD chunking
  const int bh = work >> 4;
  const int pr = work & 15;
  const int b = bh >> 4, h = bh & 15;
  const size_t base = ((size_t)b * S_) * D_ + (size_t)h * HD_;
  attn_body(Q, Kd, V, O, base, base, D_, D_, 64 * (31 - pr));
  attn_body(Q, Kd, V, O, base, base, D_, D_, 64 * pr);
}

// grouped fallback
__global__ __launch_bounds__(256) void k_attn_g(const u16* __restrict__ Q,
                                                const u16* __restrict__ Kd,
                                                const u16* __restrict__ V,
                                                u16* __restrict__ O, int g) {
  const int by = blockIdx.y;
  const int b = by >> 2, hh = by & 3;
  const size_t base_in = ((size_t)b * S_) * GW + (size_t)hh * HD_;
  const size_t base_out = ((size_t)b * S_) * D_ + (size_t)(g * 4 + hh) * HD_;
  attn_body(Q, Kd, V, O, base_in, base_out, GW, D_, blockIdx.x * 64);
}

extern "C" void kernel_launch(void* const* d_in, const int* in_sizes, int n_in,
                              void* d_out, int out_size, void* d_ws,
                              size_t ws_size, hipStream_t stream) {
  (void)in_sizes; (void)n_in; (void)out_size;
  const float* x = (const float*)d_in[0];
  const float* wq = (const float*)d_in[1];
  const float* bq = (const float*)d_in[2];
  const float* wk = (const float*)d_in[3];
  const float* bk = (const float*)d_in[4];
  const float* wv = (const float*)d_in[5];
  const float* bv = (const float*)d_in[6];
  const float* wo = (const float*)d_in[7];
  const float* bo = (const float*)d_in[8];
  float* out = (float*)d_out;

  const size_t XB = (size_t)B_ * S_ * D_ * 2;  // 16,777,216: bf16 [4096,2048]
  const size_t WB3 = 3 * (size_t)D_ * D_ * 2;  // 25,165,824: bf16 wqkv
  const size_t WB1 = (size_t)D_ * D_ * 2;      // 8,388,608:  bf16 wo
  char* ws = (char*)d_ws;
  char* ob = (char*)d_out;

  // Tier selection by ws_size. d_out (33.55 MB) doubles as scratch for
  // xb/v until the final GEMM overwrites it (final GEMM reads only ao+w+b).
  u16 *xb, *q, *k, *v, *wqkvb = nullptr, *wob = nullptr;
  int tier;
  if (ws_size >= 4 * XB + WB3 + WB1) {         // 100.7 MB: all in ws
    xb = (u16*)ws; q = (u16*)(ws + XB); k = (u16*)(ws + 2 * XB);
    v = (u16*)(ws + 3 * XB);
    wqkvb = (u16*)(ws + 4 * XB); wob = (u16*)(ws + 4 * XB + WB3);
    tier = 1;
  } else if (ws_size >= 3 * XB + WB3 + WB1) {  // 83.9 MB: xb in d_out
    xb = (u16*)ob;
    q = (u16*)ws; k = (u16*)(ws + XB); v = (u16*)(ws + 2 * XB);
    wqkvb = (u16*)(ws + 3 * XB); wob = (u16*)(ws + 3 * XB + WB3);
    tier = 1;
  } else if (ws_size >= 2 * XB + WB3 + WB1) {  // 67.1 MB: xb+v in d_out
    xb = (u16*)ob; v = (u16*)(ob + XB);
    q = (u16*)ws; k = (u16*)(ws + XB);
    wqkvb = (u16*)(ws + 2 * XB); wob = (u16*)(ws + 2 * XB + WB3);
    tier = 1;
  } else if (ws_size >= 2 * XB) {              // 33.6 MB: x-only pre-convert
    xb = (u16*)ob; v = (u16*)(ob + XB);
    q = (u16*)ws; k = (u16*)(ws + XB);
    tier = 2;
  } else {
    tier = 3;
  }

  if (tier == 1) {
    dim3 gc(4096, 5);
    k_cvt_all<<<gc, 256, 0, stream>>>(x, wq, wk, wv, wo, xb, wqkvb, wob);
    dim3 g1(16, 32, 3);
    k_gemm_qkv_bb<<<g1, 256, 0, stream>>>(xb, wqkvb, bq, bk, bv, q, k, v);
    k_rope_full<<<16384, 256, 0, stream>>>(q, k);
    dim3 g2(16, 32);
    k_attn_full<<<g2, 256, 0, stream>>>(q, k, v, q);
    dim3 g3(16, 32);
    k_gemm_out_bb<<<g3, 256, 0, stream>>>(q, wob, bo, out);
  } else if (tier == 2) {
    dim3 gc(4096, 1);
    k_cvt_all<<<gc, 256, 0, stream>>>(x, wq, wk, wv, wo, xb, xb, xb);
    dim3 g1(16, 32, 3);
    k_gemm_qkv_xb<<<g1, 256, 0, stream>>>(xb, wq, bq, wk, bk, wv, bv, q, k, v);
    k_rope_full<<<16384, 256, 0, stream>>>(q, k);
    dim3 g2(16, 32);
    k_attn_full<<<g2, 256, 0, stream>>>(q, k, v, q);
    dim3 g3(16, 32);
    k_gemm_out<<<g3, 256, 0, stream>>>(q, wo, bo, out);
  } else {
    // Proven R5 grouped fallback: ao in ws; compact q/k/v in d_out.
    u16* qg = (u16*)ob;
    u16* kg = qg + (size_t)(B_ * S_) * GW;
    u16* vg = kg + (size_t)(B_ * S_) * GW;
    u16* ao = (u16*)ws;
    for (int g = 0; g < 4; ++g) {
      dim3 g1(4, 32, 3);
      k_gemm_qkv_g<<<g1, 256, 0, stream>>>(x, wq, bq, wk, bk, wv, bv, qg, kg, vg, g);
      k_rope_g<<<4096, 256, 0, stream>>>(qg, kg);
      dim3 g2(32, 8);
      k_attn_g<<<g2, 256, 0, stream>>>(qg, kg, vg, ao, g);
    }
    dim3 g3(16, 32);
    k_gemm_out<<<g3, 256, 0, stream>>>(ao, wo, bo, out);
  }
}

// Round 9
// 292.954 us; speedup vs baseline: 2.8681x; 1.1618x over previous
//
#include <hip/hip_runtime.h>

typedef unsigned short u16;
typedef short bf16x8 __attribute__((ext_vector_type(8)));
typedef float f32x4 __attribute__((ext_vector_type(4)));

#define B_ 2
#define S_ 2048
#define D_ 2048
#define HD_ 128
#define GW 512   // head-group width for fallback path
#define KB 64    // KV tile rows
#define VST 72   // Vt row stride (u16), conflict-free & 16B-aligned rows
#define PST 72   // Ps row stride (u16)

__device__ __forceinline__ float bf2f(u16 h) {
  unsigned u = ((unsigned)h) << 16;
  return __builtin_bit_cast(float, u);
}
__device__ __forceinline__ u16 f2bf(float f) {
  unsigned u = __builtin_bit_cast(unsigned, f);
  u += 0x7FFF + ((u >> 16) & 1);
  return (u16)(u >> 16);
}
__device__ __forceinline__ bf16x8 cvt8(const float* p) {
  float4 a = *(const float4*)p;
  float4 b = *(const float4*)(p + 4);
  bf16x8 r;
  r[0] = (short)f2bf(a.x); r[1] = (short)f2bf(a.y);
  r[2] = (short)f2bf(a.z); r[3] = (short)f2bf(a.w);
  r[4] = (short)f2bf(b.x); r[5] = (short)f2bf(b.y);
  r[6] = (short)f2bf(b.z); r[7] = (short)f2bf(b.w);
  return r;
}

__device__ __forceinline__ void gload16(const void* g, void* lds) {
  __builtin_amdgcn_global_load_lds(
      (const __attribute__((address_space(1))) unsigned*)g,
      (__attribute__((address_space(3))) unsigned*)lds, 16, 0, 0);
}

__device__ __forceinline__ f32x4 mfma16(bf16x8 a, bf16x8 b, f32x4 c) {
  return __builtin_amdgcn_mfma_f32_16x16x32_bf16(a, b, c, 0, 0, 0);
}

// ---------------- f32 -> bf16 bulk convert. Grid (4096, nslices).
__global__ void k_cvt_all(const float* __restrict__ x, const float* __restrict__ wq,
                          const float* __restrict__ wk, const float* __restrict__ wv,
                          const float* __restrict__ wo, u16* __restrict__ xb,
                          u16* __restrict__ wqkvb, u16* __restrict__ wob) {
  const int slice = blockIdx.y;
  const int i = blockIdx.x * 256 + threadIdx.x;
  const float* src;
  u16* dst;
  int n8;
  if (slice == 0) { src = x; dst = xb; n8 = 1048576; }
  else if (slice == 1) { src = wq; dst = wqkvb; n8 = 524288; }
  else if (slice == 2) { src = wk; dst = wqkvb + 4194304; n8 = 524288; }
  else if (slice == 3) { src = wv; dst = wqkvb + 8388608; n8 = 524288; }
  else { src = wo; dst = wob; n8 = 524288; }
  if (i < n8) *(bf16x8*)(dst + (size_t)i * 8) = cvt8(src + (size_t)i * 8);
}

// ---------------- GEMM: C = A(M,2048) @ W(N,2048)^T + bias (m97 structure)
template <int AM, int WM, int CM>
__device__ __forceinline__ void gemm_body(const void* Ap, const void* Wp,
                                          const float* __restrict__ bias,
                                          void* Cp, int ldc) {
  constexpr int K = 2048;
  __shared__ u16 As[128 * 32];
  __shared__ u16 Bs[128 * 32];
  const int t = threadIdx.x;
  const int w = t >> 6, l = t & 63, lr = l & 15, lg = l >> 4;
  const int m0 = blockIdx.y * 128, n0 = blockIdx.x * 128;
  const int wr = w >> 1, wc = w & 1;

  f32x4 acc[4][4];
#pragma unroll
  for (int i = 0; i < 4; ++i)
#pragma unroll
    for (int j = 0; j < 4; ++j) acc[i][j] = f32x4{0.f, 0.f, 0.f, 0.f};

  const int rowA0 = t >> 2, ko0 = (t & 3) * 8;
  const int rowA1 = (t + 256) >> 2, ko1 = ((t + 256) & 3) * 8;

  for (int kt = 0; kt < K; kt += 32) {
    if constexpr (AM == 1) {
      const u16* A = (const u16*)Ap;
      gload16(A + (size_t)(m0 + rowA0) * K + kt + ko0, (char*)As + (size_t)w * 1024);
      gload16(A + (size_t)(m0 + rowA1) * K + kt + ko1, (char*)As + (size_t)(w + 4) * 1024);
    } else {
      const float* A = (const float*)Ap;
      *(bf16x8*)((char*)As + (size_t)t * 16) = cvt8(A + (size_t)(m0 + rowA0) * K + kt + ko0);
      *(bf16x8*)((char*)As + (size_t)(t + 256) * 16) = cvt8(A + (size_t)(m0 + rowA1) * K + kt + ko1);
    }
    if constexpr (WM == 1) {
      const u16* W = (const u16*)Wp;
      gload16(W + (size_t)(n0 + rowA0) * K + kt + ko0, (char*)Bs + (size_t)w * 1024);
      gload16(W + (size_t)(n0 + rowA1) * K + kt + ko1, (char*)Bs + (size_t)(w + 4) * 1024);
    } else {
      const float* W = (const float*)Wp;
      *(bf16x8*)((char*)Bs + (size_t)t * 16) = cvt8(W + (size_t)(n0 + rowA0) * K + kt + ko0);
      *(bf16x8*)((char*)Bs + (size_t)(t + 256) * 16) = cvt8(W + (size_t)(n0 + rowA1) * K + kt + ko1);
    }
    __syncthreads();

    bf16x8 af[4], bw[4];
#pragma unroll
    for (int i = 0; i < 4; ++i) {
      af[i] = *(const bf16x8*)(As + (size_t)(wr * 64 + i * 16 + lr) * 32 + lg * 8);
      bw[i] = *(const bf16x8*)(Bs + (size_t)(wc * 64 + i * 16 + lr) * 32 + lg * 8);
    }
#pragma unroll
    for (int i = 0; i < 4; ++i)
#pragma unroll
      for (int j = 0; j < 4; ++j)
        acc[i][j] = mfma16(af[i], bw[j], acc[i][j]);
    __syncthreads();
  }

#pragma unroll
  for (int i = 0; i < 4; ++i) {
#pragma unroll
    for (int j = 0; j < 4; ++j) {
      const int col = n0 + wc * 64 + j * 16 + lr;
      const float bv = bias[col];
      const int row = m0 + wr * 64 + i * 16 + lg * 4;
#pragma unroll
      for (int r = 0; r < 4; ++r) {
        if constexpr (CM == 1)
          ((float*)Cp)[(size_t)(row + r) * ldc + col] = acc[i][j][r] + bv;
        else
          ((u16*)Cp)[(size_t)(row + r) * ldc + col] = f2bf(acc[i][j][r] + bv);
      }
    }
  }
}

__global__ __launch_bounds__(256) void k_gemm_qkv_bb(
    const u16* __restrict__ xb, const u16* __restrict__ wqkvb,
    const float* __restrict__ bq, const float* __restrict__ bk,
    const float* __restrict__ bv, u16* __restrict__ q, u16* __restrict__ k,
    u16* __restrict__ v) {
  const int z = blockIdx.z;
  const u16* W = wqkvb + (size_t)z * D_ * D_;
  const float* bias = z == 0 ? bq : (z == 1 ? bk : bv);
  u16* C = z == 0 ? q : (z == 1 ? k : v);
  gemm_body<1, 1, 0>(xb, W, bias, C, D_);
}

__global__ __launch_bounds__(256) void k_gemm_out_bb(
    const u16* __restrict__ ao, const u16* __restrict__ wob,
    const float* __restrict__ bo, float* __restrict__ out) {
  gemm_body<1, 1, 1>(ao, wob, bo, out, D_);
}

__global__ __launch_bounds__(256) void k_gemm_qkv_xb(
    const u16* __restrict__ xb, const float* __restrict__ wq,
    const float* __restrict__ bq, const float* __restrict__ wk,
    const float* __restrict__ bk, const float* __restrict__ wv,
    const float* __restrict__ bv, u16* __restrict__ q, u16* __restrict__ k,
    u16* __restrict__ v) {
  const int z = blockIdx.z;
  const float* W = z == 0 ? wq : (z == 1 ? wk : wv);
  const float* bias = z == 0 ? bq : (z == 1 ? bk : bv);
  u16* C = z == 0 ? q : (z == 1 ? k : v);
  gemm_body<1, 0, 0>(xb, W, bias, C, D_);
}

__global__ __launch_bounds__(256) void k_gemm_out(const u16* __restrict__ ao,
                                                  const float* __restrict__ wo,
                                                  const float* __restrict__ bo,
                                                  float* __restrict__ out) {
  gemm_body<1, 0, 1>(ao, wo, bo, out, D_);
}

__global__ __launch_bounds__(256) void k_gemm_qkv_g(
    const float* __restrict__ x, const float* __restrict__ wq,
    const float* __restrict__ bq, const float* __restrict__ wk,
    const float* __restrict__ bk, const float* __restrict__ wv,
    const float* __restrict__ bv, u16* __restrict__ qg, u16* __restrict__ kg,
    u16* __restrict__ vg, int g) {
  const int z = blockIdx.z;
  const float* W = (z == 0 ? wq : (z == 1 ? wk : wv)) + (size_t)g * GW * D_;
  const float* bias = (z == 0 ? bq : (z == 1 ? bk : bv)) + g * GW;
  u16* C = z == 0 ? qg : (z == 1 ? kg : vg);
  gemm_body<0, 0, 0>(x, W, bias, C, GW);
}

// ---------------- RoPE (interleaved) in place
__device__ __forceinline__ void rope_one(u16* p, float cv, float sv) {
  unsigned u = *(const unsigned*)p;
  float x1 = bf2f((u16)(u & 0xffff)), x2 = bf2f((u16)(u >> 16));
  unsigned r = (unsigned)f2bf(x1 * cv - x2 * sv) |
               ((unsigned)f2bf(x1 * sv + x2 * cv) << 16);
  *(unsigned*)p = r;
}

__global__ void k_rope_full(u16* q, u16* kk) {
  const int idx = blockIdx.x * 256 + threadIdx.x;
  const int i = idx & 63;
  const int hh = (idx >> 6) & 15;
  const int bs = idx >> 10;
  const int s = bs & (S_ - 1);
  const float freq = expf(-(float)i * 0.14391157f);
  float sv, cv;
  sincosf((float)s * freq, &sv, &cv);
  const size_t off = (size_t)bs * D_ + (size_t)hh * HD_ + 2 * i;
  rope_one(q + off, cv, sv);
  rope_one(kk + off, cv, sv);
}

__global__ void k_rope_g(u16* q, u16* kk) {
  const int idx = blockIdx.x * 256 + threadIdx.x;
  const int i = idx & 63;
  const int hh = (idx >> 6) & 3;
  const int bs = idx >> 8;
  const int s = bs & (S_ - 1);
  const float freq = expf(-(float)i * 0.14391157f);
  float sv, cv;
  sincosf((float)s * freq, &sv, &cv);
  const size_t off = (size_t)bs * GW + (size_t)hh * HD_ + 2 * i;
  rope_one(q + off, cv, sv);
  rope_one(kk + off, cv, sv);
}

// ---------------- Flash attention (causal), swapped-QK^T in-register softmax.
// KV tiles of 64. K staged swizzled via global_load_lds; V packed-transposed.
// Per lane: q-row = q0+w*16+lr owns softmax stats (S computed as mfma(K,Q) ->
// lane holds S[k=16h+lg*4+r][q=lr]). O may alias Q (disjoint regions).
__device__ __forceinline__ void attn_body(const u16* Q, const u16* Kd,
                                          const u16* V, u16* O,
                                          size_t base_in, size_t base_out,
                                          int ld_in, int ld_out, int q0) {
  const int t = threadIdx.x, w = t >> 6, l = t & 63, lr = l & 15, lg = l >> 4;

  __shared__ u16 Ks[KB * HD_];      // [64][128], chunk-XOR swizzled
  __shared__ u16 Vt[HD_ * VST];     // transposed [128][72]
  __shared__ u16 Ps[4][16 * PST];   // per-wave P tile [16 q][64 k + pad]

  bf16x8 qf[4];
  {
    const u16* qp = Q + base_in + (size_t)(q0 + w * 16 + lr) * ld_in;
#pragma unroll
    for (int ds = 0; ds < 4; ++ds)
      qf[ds] = *(const bf16x8*)(qp + ds * 32 + lg * 8);
  }

  f32x4 oacc[8];
#pragma unroll
  for (int f = 0; f < 8; ++f) oacc[f] = f32x4{0.f, 0.f, 0.f, 0.f};
  float mrow = -1e30f, lrow = 0.f;  // per-lane, q-row = q0+w*16+lr

  const int qrow = q0 + w * 16 + lr;
  const int ntiles = q0 / KB + 1;
  const float sc = 0.08838834764831845f;  // 1/sqrt(128)

  for (int tkv = 0; tkv < ntiles; ++tkv) {
    const int kv0 = tkv * KB;
    // stage K (16KB) with XOR-swizzled global source, 4 rounds
#pragma unroll
    for (int r = 0; r < 4; ++r) {
      const int c = t + 256 * r;
      const int row = c >> 4, c16 = c & 15;
      const int gc = c16 ^ (row & 7);
      gload16(Kd + base_in + (size_t)(kv0 + row) * ld_in + gc * 8,
              (char*)Ks + (size_t)(w + 4 * r) * 1024);
    }
    // stage V transposed: pairs of k-rows packed as u32 writes
#pragma unroll
    for (int r = 0; r < 2; ++r) {
      const int c = t + 256 * r;
      const int kk2 = (c & 31) * 2, d0 = (c >> 5) * 8;
      bf16x8 v0 = *(const bf16x8*)(V + base_in + (size_t)(kv0 + kk2) * ld_in + d0);
      bf16x8 v1 = *(const bf16x8*)(V + base_in + (size_t)(kv0 + kk2 + 1) * ld_in + d0);
#pragma unroll
      for (int j = 0; j < 8; ++j) {
        unsigned pk = (unsigned)(unsigned short)v0[j] |
                      ((unsigned)(unsigned short)v1[j] << 16);
        *(unsigned*)&Vt[(size_t)(d0 + j) * VST + kk2] = pk;
      }
    }
    __syncthreads();

    // QK^T swapped: s_h = mfma(K_h, Q) -> lane holds S[k=16h+lg*4+r][q=lr]
    float p[16];
#pragma unroll
    for (int h = 0; h < 4; ++h) {
      f32x4 s = {0.f, 0.f, 0.f, 0.f};
#pragma unroll
      for (int ds = 0; ds < 4; ++ds) {
        const int ch = (ds * 4 + lg) ^ (lr & 7);
        bf16x8 kf = *(const bf16x8*)(Ks + (size_t)(h * 16 + lr) * HD_ + ch * 8);
        s = mfma16(kf, qf[ds], s);
      }
#pragma unroll
      for (int r = 0; r < 4; ++r) p[h * 4 + r] = s[r] * sc;
    }
    // causal mask (skip entirely for fully-unmasked tiles; wave-uniform)
    if (kv0 + KB - 1 > q0 + w * 16) {
#pragma unroll
      for (int h = 0; h < 4; ++h)
#pragma unroll
        for (int r = 0; r < 4; ++r)
          if (kv0 + h * 16 + lg * 4 + r > qrow) p[h * 4 + r] = -1e30f;
    }
    // row max: 15 in-lane + 2 shfl
    float pm = p[0];
#pragma unroll
    for (int i = 1; i < 16; ++i) pm = fmaxf(pm, p[i]);
    pm = fmaxf(pm, __shfl_xor(pm, 16, 64));
    pm = fmaxf(pm, __shfl_xor(pm, 32, 64));
    const float mn = fmaxf(mrow, pm);
    const float scl = __expf(mrow - mn);
    mrow = mn;
    float rs = 0.f;
#pragma unroll
    for (int i = 0; i < 16; ++i) {
      p[i] = __expf(p[i] - mn);
      rs += p[i];
    }
    rs += __shfl_xor(rs, 16, 64);
    rs += __shfl_xor(rs, 32, 64);
    lrow = lrow * scl + rs;
    // rescale oacc: row j needs scl of q-row lg*4+j (held by lane lg*4+j)
    float sj[4];
#pragma unroll
    for (int j = 0; j < 4; ++j) sj[j] = __shfl(scl, lg * 4 + j, 64);
#pragma unroll
    for (int f = 0; f < 8; ++f)
#pragma unroll
      for (int j = 0; j < 4; ++j) oacc[f][j] *= sj[j];
    // P -> LDS (conflict-free scalar stores), then PV
#pragma unroll
    for (int h = 0; h < 4; ++h)
#pragma unroll
      for (int r = 0; r < 4; ++r)
        Ps[w][lr * PST + h * 16 + lg * 4 + r] = f2bf(p[h * 4 + r]);
    bf16x8 pf0 = *(const bf16x8*)&Ps[w][lr * PST + lg * 8];
    bf16x8 pf1 = *(const bf16x8*)&Ps[w][lr * PST + 32 + lg * 8];
#pragma unroll
    for (int f = 0; f < 8; ++f) {
      bf16x8 vf0 = *(const bf16x8*)&Vt[(size_t)(f * 16 + lr) * VST + lg * 8];
      bf16x8 vf1 = *(const bf16x8*)&Vt[(size_t)(f * 16 + lr) * VST + 32 + lg * 8];
      oacc[f] = mfma16(pf0, vf0, oacc[f]);
      oacc[f] = mfma16(pf1, vf1, oacc[f]);
    }
    __syncthreads();
  }

  const float inv = 1.0f / lrow;
  float ij[4];
#pragma unroll
  for (int j = 0; j < 4; ++j) ij[j] = __shfl(inv, lg * 4 + j, 64);
  u16* Op = O + base_out;
#pragma unroll
  for (int f = 0; f < 8; ++f)
#pragma unroll
    for (int j = 0; j < 4; ++j)
      Op[(size_t)(q0 + w * 16 + lg * 4 + j) * ld_out + f * 16 + lr] =
          f2bf(oacc[f][j] * ij[j]);
}

// merged, triangular-paired: uniform 33 KV-tile iters/block; XCD-chunked remap.
__global__ __launch_bounds__(256) void k_attn_full(const u16* Q, const u16* Kd,
                                                   const u16* V, u16* O) {
  const int lin = blockIdx.y * gridDim.x + blockIdx.x;  // grid (16, 32) = 512
  const int work = (lin & 7) * 64 + (lin >> 3);         // bijective XCD chunking
  const int bh = work >> 4;
  const int pr = work & 15;
  const int b = bh >> 4, h = bh & 15;
  const size_t base = ((size_t)b * S_) * D_ + (size_t)h * HD_;
  attn_body(Q, Kd, V, O, base, base, D_, D_, 64 * (31 - pr));
  attn_body(Q, Kd, V, O, base, base, D_, D_, 64 * pr);
}

// grouped fallback
__global__ __launch_bounds__(256) void k_attn_g(const u16* __restrict__ Q,
                                                const u16* __restrict__ Kd,
                                                const u16* __restrict__ V,
                                                u16* __restrict__ O, int g) {
  const int by = blockIdx.y;
  const int b = by >> 2, hh = by & 3;
  const size_t base_in = ((size_t)b * S_) * GW + (size_t)hh * HD_;
  const size_t base_out = ((size_t)b * S_) * D_ + (size_t)(g * 4 + hh) * HD_;
  attn_body(Q, Kd, V, O, base_in, base_out, GW, D_, blockIdx.x * 64);
}

extern "C" void kernel_launch(void* const* d_in, const int* in_sizes, int n_in,
                              void* d_out, int out_size, void* d_ws,
                              size_t ws_size, hipStream_t stream) {
  (void)in_sizes; (void)n_in; (void)out_size;
  const float* x = (const float*)d_in[0];
  const float* wq = (const float*)d_in[1];
  const float* bq = (const float*)d_in[2];
  const float* wk = (const float*)d_in[3];
  const float* bk = (const float*)d_in[4];
  const float* wv = (const float*)d_in[5];
  const float* bv = (const float*)d_in[6];
  const float* wo = (const float*)d_in[7];
  const float* bo = (const float*)d_in[8];
  float* out = (float*)d_out;

  const size_t XB = (size_t)B_ * S_ * D_ * 2;  // 16,777,216
  const size_t WB3 = 3 * (size_t)D_ * D_ * 2;  // 25,165,824
  const size_t WB1 = (size_t)D_ * D_ * 2;      // 8,388,608
  char* ws = (char*)d_ws;
  char* ob = (char*)d_out;

  u16 *xb, *q, *k, *v, *wqkvb = nullptr, *wob = nullptr;
  int tier;
  if (ws_size >= 4 * XB + WB3 + WB1) {
    xb = (u16*)ws; q = (u16*)(ws + XB); k = (u16*)(ws + 2 * XB);
    v = (u16*)(ws + 3 * XB);
    wqkvb = (u16*)(ws + 4 * XB); wob = (u16*)(ws + 4 * XB + WB3);
    tier = 1;
  } else if (ws_size >= 3 * XB + WB3 + WB1) {
    xb = (u16*)ob;
    q = (u16*)ws; k = (u16*)(ws + XB); v = (u16*)(ws + 2 * XB);
    wqkvb = (u16*)(ws + 3 * XB); wob = (u16*)(ws + 3 * XB + WB3);
    tier = 1;
  } else if (ws_size >= 2 * XB + WB3 + WB1) {
    xb = (u16*)ob; v = (u16*)(ob + XB);
    q = (u16*)ws; k = (u16*)(ws + XB);
    wqkvb = (u16*)(ws + 2 * XB); wob = (u16*)(ws + 2 * XB + WB3);
    tier = 1;
  } else if (ws_size >= 2 * XB) {
    xb = (u16*)ob; v = (u16*)(ob + XB);
    q = (u16*)ws; k = (u16*)(ws + XB);
    tier = 2;
  } else {
    tier = 3;
  }

  if (tier == 1) {
    dim3 gc(4096, 5);
    k_cvt_all<<<gc, 256, 0, stream>>>(x, wq, wk, wv, wo, xb, wqkvb, wob);
    dim3 g1(16, 32, 3);
    k_gemm_qkv_bb<<<g1, 256, 0, stream>>>(xb, wqkvb, bq, bk, bv, q, k, v);
    k_rope_full<<<16384, 256, 0, stream>>>(q, k);
    dim3 g2(16, 32);
    k_attn_full<<<g2, 256, 0, stream>>>(q, k, v, q);
    dim3 g3(16, 32);
    k_gemm_out_bb<<<g3, 256, 0, stream>>>(q, wob, bo, out);
  } else if (tier == 2) {
    dim3 gc(4096, 1);
    k_cvt_all<<<gc, 256, 0, stream>>>(x, wq, wk, wv, wo, xb, xb, xb);
    dim3 g1(16, 32, 3);
    k_gemm_qkv_xb<<<g1, 256, 0, stream>>>(xb, wq, bq, wk, bk, wv, bv, q, k, v);
    k_rope_full<<<16384, 256, 0, stream>>>(q, k);
    dim3 g2(16, 32);
    k_attn_full<<<g2, 256, 0, stream>>>(q, k, v, q);
    dim3 g3(16, 32);
    k_gemm_out<<<g3, 256, 0, stream>>>(q, wo, bo, out);
  } else {
    u16* qg = (u16*)ob;
    u16* kg = qg + (size_t)(B_ * S_) * GW;
    u16* vg = kg + (size_t)(B_ * S_) * GW;
    u16* ao = (u16*)ws;
    for (int g = 0; g < 4; ++g) {
      dim3 g1(4, 32, 3);
      k_gemm_qkv_g<<<g1, 256, 0, stream>>>(x, wq, bq, wk, bk, wv, bv, qg, kg, vg, g);
      k_rope_g<<<4096, 256, 0, stream>>>(qg, kg);
      dim3 g2(32, 8);
      k_attn_g<<<g2, 256, 0, stream>>>(qg, kg, vg, ao, g);
    }
    dim3 g3(16, 32);
    k_gemm_out<<<g3, 256, 0, stream>>>(ao, wo, bo, out);
  }
}

// Round 10
// 280.008 us; speedup vs baseline: 3.0007x; 1.0462x over previous
//
#include <hip/hip_runtime.h>

typedef unsigned short u16;
typedef short bf16x8 __attribute__((ext_vector_type(8)));
typedef float f32x4 __attribute__((ext_vector_type(4)));

#define B_ 2
#define S_ 2048
#define D_ 2048
#define HD_ 128
#define GW 512   // head-group width for fallback path
#define KB 64    // KV tile rows
#define VST 72   // Vt row stride (u16)
#define PST 72   // Ps row stride (u16)

__device__ __forceinline__ float bf2f(u16 h) {
  unsigned u = ((unsigned)h) << 16;
  return __builtin_bit_cast(float, u);
}
__device__ __forceinline__ u16 f2bf(float f) {
  unsigned u = __builtin_bit_cast(unsigned, f);
  u += 0x7FFF + ((u >> 16) & 1);
  return (u16)(u >> 16);
}
__device__ __forceinline__ bf16x8 cvt8(const float* p) {
  float4 a = *(const float4*)p;
  float4 b = *(const float4*)(p + 4);
  bf16x8 r;
  r[0] = (short)f2bf(a.x); r[1] = (short)f2bf(a.y);
  r[2] = (short)f2bf(a.z); r[3] = (short)f2bf(a.w);
  r[4] = (short)f2bf(b.x); r[5] = (short)f2bf(b.y);
  r[6] = (short)f2bf(b.z); r[7] = (short)f2bf(b.w);
  return r;
}

__device__ __forceinline__ void gload16(const void* g, void* lds) {
  __builtin_amdgcn_global_load_lds(
      (const __attribute__((address_space(1))) unsigned*)g,
      (__attribute__((address_space(3))) unsigned*)lds, 16, 0, 0);
}

__device__ __forceinline__ f32x4 mfma16(bf16x8 a, bf16x8 b, f32x4 c) {
  return __builtin_amdgcn_mfma_f32_16x16x32_bf16(a, b, c, 0, 0, 0);
}

// ---------------- f32 -> bf16 bulk convert + RoPE table. Grid (4096, ny).
// slice 0: x; 1..3: wq/wk/wv -> wqkvb; 4: wo -> wob (if wob); 5: tab (if tab).
__global__ void k_cvt_all(const float* __restrict__ x, const float* __restrict__ wq,
                          const float* __restrict__ wk, const float* __restrict__ wv,
                          const float* __restrict__ wo, u16* __restrict__ xb,
                          u16* __restrict__ wqkvb, u16* wob, float2* tab) {
  const int slice = blockIdx.y;
  const int i = blockIdx.x * 256 + threadIdx.x;
  if (slice == 5) {
    if (tab != nullptr && i < 131072) {  // 2048 x 64
      const int s = i >> 6, ip = i & 63;
      const float freq = expf(-(float)ip * 0.14391157f);  // ln(10000)/64
      float sv, cv;
      sincosf((float)s * freq, &sv, &cv);
      tab[i] = make_float2(cv, sv);
    }
    return;
  }
  if (slice == 4 && wob == nullptr) return;
  const float* src;
  u16* dst;
  int n8;
  if (slice == 0) { src = x; dst = xb; n8 = 1048576; }
  else if (slice == 1) { src = wq; dst = wqkvb; n8 = 524288; }
  else if (slice == 2) { src = wk; dst = wqkvb + 4194304; n8 = 524288; }
  else if (slice == 3) { src = wv; dst = wqkvb + 8388608; n8 = 524288; }
  else { src = wo; dst = wob; n8 = 524288; }
  if (i < n8) *(bf16x8*)(dst + (size_t)i * 8) = cvt8(src + (size_t)i * 8);
}

// ---------------- GEMM: C = A(M,2048) @ W(N,2048)^T + bias (m97 structure)
// AM/WM: 1 = bf16 via global_load_lds, 0 = f32 reg-stage+cvt. CM: 0 bf16/1 f32.
// tab != nullptr (CM=0 only): apply interleaved RoPE in epilogue.
template <int AM, int WM, int CM>
__device__ __forceinline__ void gemm_body(const void* Ap, const void* Wp,
                                          const float* __restrict__ bias,
                                          void* Cp, int ldc,
                                          const float2* __restrict__ tab) {
  constexpr int K = 2048;
  __shared__ u16 As[128 * 32];
  __shared__ u16 Bs[128 * 32];
  const int t = threadIdx.x;
  const int w = t >> 6, l = t & 63, lr = l & 15, lg = l >> 4;
  const int m0 = blockIdx.y * 128, n0 = blockIdx.x * 128;
  const int wr = w >> 1, wc = w & 1;

  f32x4 acc[4][4];
#pragma unroll
  for (int i = 0; i < 4; ++i)
#pragma unroll
    for (int j = 0; j < 4; ++j) acc[i][j] = f32x4{0.f, 0.f, 0.f, 0.f};

  const int rowA0 = t >> 2, ko0 = (t & 3) * 8;
  const int rowA1 = (t + 256) >> 2, ko1 = ((t + 256) & 3) * 8;

  for (int kt = 0; kt < K; kt += 32) {
    if constexpr (AM == 1) {
      const u16* A = (const u16*)Ap;
      gload16(A + (size_t)(m0 + rowA0) * K + kt + ko0, (char*)As + (size_t)w * 1024);
      gload16(A + (size_t)(m0 + rowA1) * K + kt + ko1, (char*)As + (size_t)(w + 4) * 1024);
    } else {
      const float* A = (const float*)Ap;
      *(bf16x8*)((char*)As + (size_t)t * 16) = cvt8(A + (size_t)(m0 + rowA0) * K + kt + ko0);
      *(bf16x8*)((char*)As + (size_t)(t + 256) * 16) = cvt8(A + (size_t)(m0 + rowA1) * K + kt + ko1);
    }
    if constexpr (WM == 1) {
      const u16* W = (const u16*)Wp;
      gload16(W + (size_t)(n0 + rowA0) * K + kt + ko0, (char*)Bs + (size_t)w * 1024);
      gload16(W + (size_t)(n0 + rowA1) * K + kt + ko1, (char*)Bs + (size_t)(w + 4) * 1024);
    } else {
      const float* W = (const float*)Wp;
      *(bf16x8*)((char*)Bs + (size_t)t * 16) = cvt8(W + (size_t)(n0 + rowA0) * K + kt + ko0);
      *(bf16x8*)((char*)Bs + (size_t)(t + 256) * 16) = cvt8(W + (size_t)(n0 + rowA1) * K + kt + ko1);
    }
    __syncthreads();

    bf16x8 af[4], bw[4];
#pragma unroll
    for (int i = 0; i < 4; ++i) {
      af[i] = *(const bf16x8*)(As + (size_t)(wr * 64 + i * 16 + lr) * 32 + lg * 8);
      bw[i] = *(const bf16x8*)(Bs + (size_t)(wc * 64 + i * 16 + lr) * 32 + lg * 8);
    }
#pragma unroll
    for (int i = 0; i < 4; ++i)
#pragma unroll
      for (int j = 0; j < 4; ++j)
        acc[i][j] = mfma16(af[i], bw[j], acc[i][j]);
    __syncthreads();
  }

#pragma unroll
  for (int i = 0; i < 4; ++i) {
#pragma unroll
    for (int j = 0; j < 4; ++j) {
      const int col = n0 + wc * 64 + j * 16 + lr;
      const float bv = bias[col];
      const int row = m0 + wr * 64 + i * 16 + lg * 4;
      if (CM == 0 && tab != nullptr) {
        const int ip = (col & 127) >> 1;
        const int odd = col & 1;
#pragma unroll
        for (int r = 0; r < 4; ++r) {
          const float v = acc[i][j][r] + bv;
          const float p = __shfl_xor(v, 1, 64);
          const float2 cs = tab[((row + r) & (S_ - 1)) * 64 + ip];
          const float o = odd ? (p * cs.y + v * cs.x) : (v * cs.x - p * cs.y);
          ((u16*)Cp)[(size_t)(row + r) * ldc + col] = f2bf(o);
        }
      } else {
#pragma unroll
        for (int r = 0; r < 4; ++r) {
          if constexpr (CM == 1)
            ((float*)Cp)[(size_t)(row + r) * ldc + col] = acc[i][j][r] + bv;
          else
            ((u16*)Cp)[(size_t)(row + r) * ldc + col] = f2bf(acc[i][j][r] + bv);
        }
      }
    }
  }
}

__global__ __launch_bounds__(256) void k_gemm_qkv_bb(
    const u16* __restrict__ xb, const u16* __restrict__ wqkvb,
    const float* __restrict__ bq, const float* __restrict__ bk,
    const float* __restrict__ bv, u16* __restrict__ q, u16* __restrict__ k,
    u16* __restrict__ v, const float2* __restrict__ tab) {
  const int z = blockIdx.z;
  const u16* W = wqkvb + (size_t)z * D_ * D_;
  const float* bias = z == 0 ? bq : (z == 1 ? bk : bv);
  u16* C = z == 0 ? q : (z == 1 ? k : v);
  gemm_body<1, 1, 0>(xb, W, bias, C, D_, z == 2 ? nullptr : tab);
}

__global__ __launch_bounds__(256) void k_gemm_out_bb(
    const u16* __restrict__ ao, const u16* __restrict__ wob,
    const float* __restrict__ bo, float* __restrict__ out) {
  gemm_body<1, 1, 1>(ao, wob, bo, out, D_, nullptr);
}

__global__ __launch_bounds__(256) void k_gemm_qkv_xb(
    const u16* __restrict__ xb, const float* __restrict__ wq,
    const float* __restrict__ bq, const float* __restrict__ wk,
    const float* __restrict__ bk, const float* __restrict__ wv,
    const float* __restrict__ bv, u16* __restrict__ q, u16* __restrict__ k,
    u16* __restrict__ v) {
  const int z = blockIdx.z;
  const float* W = z == 0 ? wq : (z == 1 ? wk : wv);
  const float* bias = z == 0 ? bq : (z == 1 ? bk : bv);
  u16* C = z == 0 ? q : (z == 1 ? k : v);
  gemm_body<1, 0, 0>(xb, W, bias, C, D_, nullptr);
}

__global__ __launch_bounds__(256) void k_gemm_out(const u16* __restrict__ ao,
                                                  const float* __restrict__ wo,
                                                  const float* __restrict__ bo,
                                                  float* __restrict__ out) {
  gemm_body<1, 0, 1>(ao, wo, bo, out, D_, nullptr);
}

__global__ __launch_bounds__(256) void k_gemm_qkv_g(
    const float* __restrict__ x, const float* __restrict__ wq,
    const float* __restrict__ bq, const float* __restrict__ wk,
    const float* __restrict__ bk, const float* __restrict__ wv,
    const float* __restrict__ bv, u16* __restrict__ qg, u16* __restrict__ kg,
    u16* __restrict__ vg, int g) {
  const int z = blockIdx.z;
  const float* W = (z == 0 ? wq : (z == 1 ? wk : wv)) + (size_t)g * GW * D_;
  const float* bias = (z == 0 ? bq : (z == 1 ? bk : bv)) + g * GW;
  u16* C = z == 0 ? qg : (z == 1 ? kg : vg);
  gemm_body<0, 0, 0>(x, W, bias, C, GW, nullptr);
}

// ---------------- RoPE (interleaved) in place, for tiers without table space
__device__ __forceinline__ void rope_one(u16* p, float cv, float sv) {
  unsigned u = *(const unsigned*)p;
  float x1 = bf2f((u16)(u & 0xffff)), x2 = bf2f((u16)(u >> 16));
  unsigned r = (unsigned)f2bf(x1 * cv - x2 * sv) |
               ((unsigned)f2bf(x1 * sv + x2 * cv) << 16);
  *(unsigned*)p = r;
}

__global__ void k_rope_full(u16* q, u16* kk) {
  const int idx = blockIdx.x * 256 + threadIdx.x;
  const int i = idx & 63;
  const int hh = (idx >> 6) & 15;
  const int bs = idx >> 10;
  const int s = bs & (S_ - 1);
  const float freq = expf(-(float)i * 0.14391157f);
  float sv, cv;
  sincosf((float)s * freq, &sv, &cv);
  const size_t off = (size_t)bs * D_ + (size_t)hh * HD_ + 2 * i;
  rope_one(q + off, cv, sv);
  rope_one(kk + off, cv, sv);
}

__global__ void k_rope_g(u16* q, u16* kk) {
  const int idx = blockIdx.x * 256 + threadIdx.x;
  const int i = idx & 63;
  const int hh = (idx >> 6) & 3;
  const int bs = idx >> 8;
  const int s = bs & (S_ - 1);
  const float freq = expf(-(float)i * 0.14391157f);
  float sv, cv;
  sincosf((float)s * freq, &sv, &cv);
  const size_t off = (size_t)bs * GW + (size_t)hh * HD_ + 2 * i;
  rope_one(q + off, cv, sv);
  rope_one(kk + off, cv, sv);
}

// ---------------- Flash attention (causal), swapped-QK^T, double-buffered
// K/V with counted vmcnt + raw barriers (prefetch 1 tile deep, never drain
// except tail). O may alias Q (disjoint regions).
__device__ __forceinline__ void attn_body(const u16* Q, const u16* Kd,
                                          const u16* V, u16* O,
                                          size_t base_in, size_t base_out,
                                          int ld_in, int ld_out, int q0) {
  const int t = threadIdx.x, w = t >> 6, l = t & 63, lr = l & 15, lg = l >> 4;

  __shared__ u16 Ks[2][KB * HD_];   // 2 x [64][128], chunk-XOR swizzled
  __shared__ u16 Vt[2][HD_ * VST];  // 2 x transposed [128][72]
  __shared__ u16 Ps[4][16 * PST];   // per-wave P tile

  bf16x8 qf[4];
  {
    const u16* qp = Q + base_in + (size_t)(q0 + w * 16 + lr) * ld_in;
#pragma unroll
    for (int ds = 0; ds < 4; ++ds)
      qf[ds] = *(const bf16x8*)(qp + ds * 32 + lg * 8);
  }

  f32x4 oacc[8];
#pragma unroll
  for (int f = 0; f < 8; ++f) oacc[f] = f32x4{0.f, 0.f, 0.f, 0.f};
  float mrow = -1e30f, lrow = 0.f;

  const int qrow = q0 + w * 16 + lr;
  const int nt = q0 / KB + 1;
  const float sc = 0.08838834764831845f;  // 1/sqrt(128)

  // staging index precompute
  const int kRow = t >> 4, kC16 = t & 15;          // used with +256*r variants
  (void)kRow; (void)kC16;
  const int c1 = t + 256;
  const int kk20 = (t & 31) * 2, d00 = (t >> 5) * 8;
  const int kk21 = (c1 & 31) * 2, d01 = (c1 >> 5) * 8;

  bf16x8 vc[4];  // V register staging (current tile)

  // ---- prologue: stage tile 0
#pragma unroll
  for (int r = 0; r < 4; ++r) {
    const int c = t + 256 * r;
    const int row = c >> 4, c16 = c & 15;
    const int gc = c16 ^ (row & 7);
    gload16(Kd + base_in + (size_t)row * ld_in + gc * 8,
            (char*)Ks[0] + (size_t)(w + 4 * r) * 1024);
  }
  vc[0] = *(const bf16x8*)(V + base_in + (size_t)kk20 * ld_in + d00);
  vc[1] = *(const bf16x8*)(V + base_in + (size_t)(kk20 + 1) * ld_in + d00);
  vc[2] = *(const bf16x8*)(V + base_in + (size_t)kk21 * ld_in + d01);
  vc[3] = *(const bf16x8*)(V + base_in + (size_t)(kk21 + 1) * ld_in + d01);

  for (int tt = 0; tt < nt; ++tt) {
    const int cur = tt & 1;
    const int kv0 = tt * KB;
    const bool more = (tt + 1 < nt);

    // issue next K tile into other buffer
    if (more) {
      const int kvn = kv0 + KB;
#pragma unroll
      for (int r = 0; r < 4; ++r) {
        const int c = t + 256 * r;
        const int row = c >> 4, c16 = c & 15;
        const int gc = c16 ^ (row & 7);
        gload16(Kd + base_in + (size_t)(kvn + row) * ld_in + gc * 8,
                (char*)Ks[cur ^ 1] + (size_t)(w + 4 * r) * 1024);
      }
      asm volatile("s_waitcnt vmcnt(4)" ::: "memory");
    } else {
      asm volatile("s_waitcnt vmcnt(0)" ::: "memory");
    }
    __builtin_amdgcn_sched_barrier(0);

    // write Vt[cur] from registers (packed u32), then issue next V reg loads
    {
      u16* vt = Vt[cur];
#pragma unroll
      for (int j = 0; j < 8; ++j) {
        unsigned p0 = (unsigned)(unsigned short)vc[0][j] |
                      ((unsigned)(unsigned short)vc[1][j] << 16);
        *(unsigned*)&vt[(size_t)(d00 + j) * VST + kk20] = p0;
        unsigned p1 = (unsigned)(unsigned short)vc[2][j] |
                      ((unsigned)(unsigned short)vc[3][j] << 16);
        *(unsigned*)&vt[(size_t)(d01 + j) * VST + kk21] = p1;
      }
    }
    if (more) {
      const int kvn = kv0 + KB;
      vc[0] = *(const bf16x8*)(V + base_in + (size_t)(kvn + kk20) * ld_in + d00);
      vc[1] = *(const bf16x8*)(V + base_in + (size_t)(kvn + kk20 + 1) * ld_in + d00);
      vc[2] = *(const bf16x8*)(V + base_in + (size_t)(kvn + kk21) * ld_in + d01);
      vc[3] = *(const bf16x8*)(V + base_in + (size_t)(kvn + kk21 + 1) * ld_in + d01);
    }
    asm volatile("s_waitcnt lgkmcnt(0)" ::: "memory");
    __builtin_amdgcn_sched_barrier(0);
    __builtin_amdgcn_s_barrier();
    __builtin_amdgcn_sched_barrier(0);

    // ---- compute tile tt from Ks[cur], Vt[cur]
    float p[16];
    __builtin_amdgcn_s_setprio(1);
#pragma unroll
    for (int h = 0; h < 4; ++h) {
      f32x4 s = {0.f, 0.f, 0.f, 0.f};
#pragma unroll
      for (int ds = 0; ds < 4; ++ds) {
        const int ch = (ds * 4 + lg) ^ (lr & 7);
        bf16x8 kf = *(const bf16x8*)(Ks[cur] + (size_t)(h * 16 + lr) * HD_ + ch * 8);
        s = mfma16(kf, qf[ds], s);
      }
#pragma unroll
      for (int r = 0; r < 4; ++r) p[h * 4 + r] = s[r] * sc;
    }
    __builtin_amdgcn_s_setprio(0);
    if (kv0 + KB - 1 > q0 + w * 16) {
#pragma unroll
      for (int h = 0; h < 4; ++h)
#pragma unroll
        for (int r = 0; r < 4; ++r)
          if (kv0 + h * 16 + lg * 4 + r > qrow) p[h * 4 + r] = -1e30f;
    }
    float pm = p[0];
#pragma unroll
    for (int i = 1; i < 16; ++i) pm = fmaxf(pm, p[i]);
    pm = fmaxf(pm, __shfl_xor(pm, 16, 64));
    pm = fmaxf(pm, __shfl_xor(pm, 32, 64));
    const float mn = fmaxf(mrow, pm);
    const float scl = __expf(mrow - mn);
    mrow = mn;
    float rs = 0.f;
#pragma unroll
    for (int i = 0; i < 16; ++i) {
      p[i] = __expf(p[i] - mn);
      rs += p[i];
    }
    rs += __shfl_xor(rs, 16, 64);
    rs += __shfl_xor(rs, 32, 64);
    lrow = lrow * scl + rs;
    float sj[4];
#pragma unroll
    for (int j = 0; j < 4; ++j) sj[j] = __shfl(scl, lg * 4 + j, 64);
#pragma unroll
    for (int f = 0; f < 8; ++f)
#pragma unroll
      for (int j = 0; j < 4; ++j) oacc[f][j] *= sj[j];
#pragma unroll
    for (int h = 0; h < 4; ++h)
#pragma unroll
      for (int r = 0; r < 4; ++r)
        Ps[w][lr * PST + h * 16 + lg * 4 + r] = f2bf(p[h * 4 + r]);
    bf16x8 pf0 = *(const bf16x8*)&Ps[w][lr * PST + lg * 8];
    bf16x8 pf1 = *(const bf16x8*)&Ps[w][lr * PST + 32 + lg * 8];
    __builtin_amdgcn_s_setprio(1);
#pragma unroll
    for (int f = 0; f < 8; ++f) {
      bf16x8 vf0 = *(const bf16x8*)&Vt[cur][(size_t)(f * 16 + lr) * VST + lg * 8];
      bf16x8 vf1 = *(const bf16x8*)&Vt[cur][(size_t)(f * 16 + lr) * VST + 32 + lg * 8];
      oacc[f] = mfma16(pf0, vf0, oacc[f]);
      oacc[f] = mfma16(pf1, vf1, oacc[f]);
    }
    __builtin_amdgcn_s_setprio(0);
    __builtin_amdgcn_sched_barrier(0);
    __builtin_amdgcn_s_barrier();
    __builtin_amdgcn_sched_barrier(0);
  }

  const float inv = 1.0f / lrow;
  float ij[4];
#pragma unroll
  for (int j = 0; j < 4; ++j) ij[j] = __shfl(inv, lg * 4 + j, 64);
  u16* Op = O + base_out;
#pragma unroll
  for (int f = 0; f < 8; ++f)
#pragma unroll
    for (int j = 0; j < 4; ++j)
      Op[(size_t)(q0 + w * 16 + lg * 4 + j) * ld_out + f * 16 + lr] =
          f2bf(oacc[f][j] * ij[j]);
}

// merged, triangular-paired: uniform work/block; XCD-chunked remap.
__global__ __launch_bounds__(256) void k_attn_full(const u16* Q, const u16* Kd,
                                                   const u16* V, u16* O) {
  const int lin = blockIdx.y * gridDim.x + blockIdx.x;  // grid (16, 32) = 512
  const int work = (lin & 7) * 64 + (lin >> 3);
  const int bh = work >> 4;
  const int pr = work & 15;
  const int b = bh >> 4, h = bh & 15;
  const size_t base = ((size_t)b * S_) * D_ + (size_t)h * HD_;
  attn_body(Q, Kd, V, O, base, base, D_, D_, 64 * (31 - pr));
  attn_body(Q, Kd, V, O, base, base, D_, D_, 64 * pr);
}

// grouped fallback
__global__ __launch_bounds__(256) void k_attn_g(const u16* __restrict__ Q,
                                                const u16* __restrict__ Kd,
                                                const u16* __restrict__ V,
                                                u16* __restrict__ O, int g) {
  const int by = blockIdx.y;
  const int b = by >> 2, hh = by & 3;
  const size_t base_in = ((size_t)b * S_) * GW + (size_t)hh * HD_;
  const size_t base_out = ((size_t)b * S_) * D_ + (size_t)(g * 4 + hh) * HD_;
  attn_body(Q, Kd, V, O, base_in, base_out, GW, D_, blockIdx.x * 64);
}

extern "C" void kernel_launch(void* const* d_in, const int* in_sizes, int n_in,
                              void* d_out, int out_size, void* d_ws,
                              size_t ws_size, hipStream_t stream) {
  (void)in_sizes; (void)n_in; (void)out_size;
  const float* x = (const float*)d_in[0];
  const float* wq = (const float*)d_in[1];
  const float* bq = (const float*)d_in[2];
  const float* wk = (const float*)d_in[3];
  const float* bk = (const float*)d_in[4];
  const float* wv = (const float*)d_in[5];
  const float* bv = (const float*)d_in[6];
  const float* wo = (const float*)d_in[7];
  const float* bo = (const float*)d_in[8];
  float* out = (float*)d_out;

  const size_t XB = (size_t)B_ * S_ * D_ * 2;  // 16,777,216
  const size_t WB3 = 3 * (size_t)D_ * D_ * 2;  // 25,165,824
  const size_t WB1 = (size_t)D_ * D_ * 2;      // 8,388,608
  const size_t TB = (size_t)S_ * 64 * 8;       // 1,048,576 rope table
  char* ws = (char*)d_ws;
  char* ob = (char*)d_out;

  u16 *xb, *q, *k, *v, *wqkvb = nullptr, *wob = nullptr;
  float2* tab = nullptr;
  int tier;
  if (ws_size >= 4 * XB + WB3 + WB1 + TB) {  // all in ws, fused rope
    xb = (u16*)ws; q = (u16*)(ws + XB); k = (u16*)(ws + 2 * XB);
    v = (u16*)(ws + 3 * XB);
    wqkvb = (u16*)(ws + 4 * XB); wob = (u16*)(ws + 4 * XB + WB3);
    tab = (float2*)(ws + 4 * XB + WB3 + WB1);
    tier = 1;
  } else if (ws_size >= 3 * XB + WB3 + WB1 + TB) {  // xb in d_out
    xb = (u16*)ob;
    q = (u16*)ws; k = (u16*)(ws + XB); v = (u16*)(ws + 2 * XB);
    wqkvb = (u16*)(ws + 3 * XB); wob = (u16*)(ws + 3 * XB + WB3);
    tab = (float2*)(ws + 3 * XB + WB3 + WB1);
    tier = 1;
  } else if (ws_size >= 2 * XB + WB3 + TB) {  // xb+v in d_out, no wob
    xb = (u16*)ob; v = (u16*)(ob + XB);
    q = (u16*)ws; k = (u16*)(ws + XB);
    wqkvb = (u16*)(ws + 2 * XB);
    tab = (float2*)(ws + 2 * XB + WB3);
    tier = 2;  // fused rope, f32-W final GEMM
  } else if (ws_size >= 2 * XB) {  // minimal: x-only pre-convert, separate rope
    xb = (u16*)ob; v = (u16*)(ob + XB);
    q = (u16*)ws; k = (u16*)(ws + XB);
    tier = 3;
  } else {
    tier = 4;
  }

  if (tier == 1 || tier == 2) {
    dim3 gc(4096, 6);
    k_cvt_all<<<gc, 256, 0, stream>>>(x, wq, wk, wv, wo, xb, wqkvb, wob, tab);
    dim3 g1(16, 32, 3);
    k_gemm_qkv_bb<<<g1, 256, 0, stream>>>(xb, wqkvb, bq, bk, bv, q, k, v, tab);
    dim3 g2(16, 32);
    k_attn_full<<<g2, 256, 0, stream>>>(q, k, v, q);
    dim3 g3(16, 32);
    if (tier == 1)
      k_gemm_out_bb<<<g3, 256, 0, stream>>>(q, wob, bo, out);
    else
      k_gemm_out<<<g3, 256, 0, stream>>>(q, wo, bo, out);
  } else if (tier == 3) {
    dim3 gc(4096, 1);
    k_cvt_all<<<gc, 256, 0, stream>>>(x, wq, wk, wv, wo, xb, xb, nullptr, nullptr);
    dim3 g1(16, 32, 3);
    k_gemm_qkv_xb<<<g1, 256, 0, stream>>>(xb, wq, bq, wk, bk, wv, bv, q, k, v);
    k_rope_full<<<16384, 256, 0, stream>>>(q, k);
    dim3 g2(16, 32);
    k_attn_full<<<g2, 256, 0, stream>>>(q, k, v, q);
    dim3 g3(16, 32);
    k_gemm_out<<<g3, 256, 0, stream>>>(q, wo, bo, out);
  } else {
    u16* qg = (u16*)ob;
    u16* kg = qg + (size_t)(B_ * S_) * GW;
    u16* vg = kg + (size_t)(B_ * S_) * GW;
    u16* ao = (u16*)ws;
    for (int g = 0; g < 4; ++g) {
      dim3 g1(4, 32, 3);
      k_gemm_qkv_g<<<g1, 256, 0, stream>>>(x, wq, bq, wk, bk, wv, bv, qg, kg, vg, g);
      k_rope_g<<<4096, 256, 0, stream>>>(qg, kg);
      dim3 g2(32, 8);
      k_attn_g<<<g2, 256, 0, stream>>>(qg, kg, vg, ao, g);
    }
    dim3 g3(16, 32);
    k_gemm_out<<<g3, 256, 0, stream>>>(ao, wo, bo, out);
  }
}